// Round 1
// baseline (2139.547 us; speedup 1.0000x reference)
//
#include <hip/hip_runtime.h>

// ---------------------------------------------------------------------------
// DensityEstimator: 3-layer neural spline flow inverse log-prob, fp32.
//
// Per layer i in (2,1,0):
//   A = L_i @ U_i  (550x550, triangular product), columns scattered by perm_i
//   z2 = z @ A^T + lu_b_i                         (gemm, BT)
//   ident = rqs_inv(z2[:,0::2]; per-feature knots)   -> identb, znext even
//   t = resnet(identb)  (5 small gemms, relu, residual)
//   p_chunk = t_chunk @ Wo + bo  (gemm), trans = rqs_inv(z2[:,1::2]; p)
//   -> znext odd cols;  lq += spline logdets
// Finalize: lq += sum(log diag) (all layers) - 0.5*D*log(2pi) - gaussian term
// ---------------------------------------------------------------------------

#define D_DIM 550
#define F_DIM 275
#define HID_DIM 128
#define OUT_DIM 6325   // F*(3*NB-1)
#define B_ROWS 4096
#define NBINS 8
#define TB_C 3.0f
#define MINB_C 0.001f
#define MIND_C 0.001f
#define DCONST_C 0.53974233f          // log(exp(0.999)-1)
#define LUEPS_C 0.001f
#define RSQRT_HID 0.08838834764831845f // 1/sqrt(128)
#define CHUNK_ROWS 1024

__device__ __forceinline__ float softplusf(float x){
    return fmaxf(x, 0.f) + log1pf(__expf(-fabsf(x)));
}

// widths/cumknots from 8 unnormalized params (softmax -> affine -> cumsum)
__device__ __forceinline__ void knots_from_u(const float* u, float* c, float* w){
    float m = u[0];
#pragma unroll
    for(int k=1;k<NBINS;k++) m = fmaxf(m, u[k]);
    float e[NBINS]; float s = 0.f;
#pragma unroll
    for(int k=0;k<NBINS;k++){ e[k] = __expf(u[k]-m); s += e[k]; }
    float inv = 1.f/s;
    float cum = 0.f;
    c[0] = -TB_C;
#pragma unroll
    for(int k=0;k<NBINS;k++){
        float v = MINB_C + (1.f - MINB_C*(float)NBINS)*e[k]*inv;
        cum += v;
        c[k+1] = 2.f*TB_C*cum - TB_C;
    }
    c[NBINS] = TB_C;  // endpoint forced (matches reference .set)
#pragma unroll
    for(int k=0;k<NBINS;k++) w[k] = c[k+1]-c[k];
}

// inverse rational-quadratic spline, one scalar. cw/w/ch/h/d: 9/8/9/8/9 entries.
__device__ __forceinline__ void rqs_inv(float x,
                                        const float* cw, const float* w,
                                        const float* ch, const float* h,
                                        const float* d,
                                        float& out, float& ld){
    bool inside = (x >= -TB_C) && (x <= TB_C);
    float xi = fminf(fmaxf(x, -TB_C), TB_C);
    // bin index in y (heights). locs[0]=-3 always <= xi; locs[8]=3+1e-6 never.
    int idx = 0;
#pragma unroll
    for(int j=1;j<NBINS;j++) idx += (xi >= ch[j]) ? 1 : 0;
    float icw=cw[0], iw=w[0], ich=ch[0], ih=h[0], d0=d[0], d1=d[1];
#pragma unroll
    for(int j=1;j<NBINS;j++){
        if(idx==j){ icw=cw[j]; iw=w[j]; ich=ch[j]; ih=h[j]; d0=d[j]; d1=d[j+1]; }
    }
    float delta = ih/iw;
    float t  = xi - ich;
    float s  = d0 + d1 - 2.f*delta;
    float a  = t*s + ih*(delta - d0);
    float b  = ih*d0 - t*s;
    float c  = -delta*t;
    float disc = b*b - 4.f*a*c;
    float root = 2.f*c / (-b - sqrtf(fmaxf(disc, 0.f)));
    float o  = root*iw + icw;
    float tm = root*(1.f-root);
    float den  = delta + s*tm;
    float dnum = delta*delta*(d1*root*root + 2.f*delta*tm + d0*(1.f-root)*(1.f-root));
    float l = 2.f*__logf(den) - __logf(dnum);
    out = inside ? o : x;
    ld  = inside ? l : 0.f;
}

// --------------------------- small setup kernels ---------------------------

// per (layer,feature) unconditional spline knots: [3*F][43]
// layout: cw[0..8], w[9..16], ch[17..25], h[26..33], d[34..42]
__global__ void build_knots_kernel(const float* __restrict__ uw_u,
                                   const float* __restrict__ uh_u,
                                   const float* __restrict__ ud_u,
                                   float* __restrict__ knots){
    int g = blockIdx.x*blockDim.x + threadIdx.x;
    if(g >= 3*F_DIM) return;
    float* kb = knots + (size_t)g*43;
    float c[9], w[8];
    knots_from_u(uw_u + (size_t)g*8, c, w);
#pragma unroll
    for(int k=0;k<9;k++) kb[k]=c[k];
#pragma unroll
    for(int k=0;k<8;k++) kb[9+k]=w[k];
    knots_from_u(uh_u + (size_t)g*8, c, w);
#pragma unroll
    for(int k=0;k<9;k++) kb[17+k]=c[k];
#pragma unroll
    for(int k=0;k<8;k++) kb[26+k]=w[k];
    float dend = MIND_C + softplusf(DCONST_C);
    kb[34]=dend; kb[42]=dend;
    const float* ud = ud_u + (size_t)g*7;
#pragma unroll
    for(int k=0;k<7;k++) kb[35+k] = MIND_C + softplusf(ud[k]);
}

// scalar: sum over all 3 layers of sum(log(softplus(lu_ud)+eps))
__global__ void logdiag_kernel(const float* __restrict__ lu_ud, float* __restrict__ outv){
    int tid = threadIdx.x;
    float s = 0.f;
    for(int k=tid; k<3*D_DIM; k+=256) s += __logf(softplusf(lu_ud[k]) + LUEPS_C);
#pragma unroll
    for(int o=32;o>0;o>>=1) s += __shfl_down(s, o);
    __shared__ float sm[4];
    if((tid&63)==0) sm[tid>>6]=s;
    __syncthreads();
    if(tid==0) outv[0] = sm[0]+sm[1]+sm[2]+sm[3];
}

// Ap[j][perm[k]] = (L@U)[j][k]   (L unit-lower, U upper w/ softplus diag)
__global__ void build_A_kernel(const float* __restrict__ lower,
                               const float* __restrict__ upper,
                               const float* __restrict__ ud,
                               const int* __restrict__ perm,
                               float* __restrict__ Ap){
    int k = blockIdx.x*blockDim.x + threadIdx.x;
    int j = blockIdx.y;
    if(k >= D_DIM) return;
    float diagk = softplusf(ud[k]) + LUEPS_C;
    int mmax = min(j,k);
    float acc = 0.f;
    for(int m=0;m<=mmax;m++){
        float lv = (m<j) ? lower[(size_t)j*D_DIM+m] : 1.f;
        float uv = (m<k) ? upper[(size_t)m*D_DIM+k] : diagk;
        acc = fmaf(lv, uv, acc);
    }
    Ap[(size_t)j*D_DIM + perm[k]] = acc;
}

// ------------------------------- gemm --------------------------------------
// C[M,N] = act(A)[M,K] @ B + bias (+ resid).  BT=0: B[K,N].  BT=1: B[N,K] (B^T).
// 64x64 tile, 16x16 threads, 4x4 micro-tile, K-tile 16.
template<int RELU, int RESID, int BT>
__global__ __launch_bounds__(256)
void gemm64(const float* __restrict__ A, const float* __restrict__ Bm,
            const float* __restrict__ bias, const float* __restrict__ Rm,
            float* __restrict__ C, int M, int N, int K){
    __shared__ float As[16][68];  // [k][m], +4 pad keeps 16B-aligned rows
    __shared__ float Bs[16][68];  // [k][n]
    int tx = threadIdx.x, ty = threadIdx.y;
    int tid = ty*16 + tx;
    int row0 = blockIdx.y*64, col0 = blockIdx.x*64;
    float acc[4][4] = {};
    for(int k0=0; k0<K; k0+=16){
        { // A tile: 64 rows x 16 k
            int r = tid>>4, c = tid&15;
#pragma unroll
            for(int i=0;i<4;i++){
                int rr = r + i*16;
                int gr = row0+rr, gc = k0+c;
                float v = (gr<M && gc<K) ? A[(size_t)gr*K+gc] : 0.f;
                if(RELU) v = fmaxf(v, 0.f);
                As[c][rr] = v;
            }
        }
        if(BT==0){ // B tile: 16 k x 64 n, row-major [K][N]
            int kk = tid>>6, c = tid&63;
#pragma unroll
            for(int i=0;i<4;i++){
                int kr = kk + i*4;
                int gk = k0+kr, gc = col0+c;
                Bs[kr][c] = (gk<K && gc<N) ? Bm[(size_t)gk*N+gc] : 0.f;
            }
        } else {   // B^T: B stored [N][K]
            int n = tid>>4, c = tid&15;
#pragma unroll
            for(int i=0;i<4;i++){
                int nn = n + i*16;
                int gn = col0+nn, gk = k0+c;
                Bs[c][nn] = (gn<N && gk<K) ? Bm[(size_t)gn*K+gk] : 0.f;
            }
        }
        __syncthreads();
#pragma unroll
        for(int kk=0;kk<16;kk++){
            float4 av = *(const float4*)&As[kk][ty*4];
            float4 bv = *(const float4*)&Bs[kk][tx*4];
            float aa[4] = {av.x, av.y, av.z, av.w};
            float bb_[4] = {bv.x, bv.y, bv.z, bv.w};
#pragma unroll
            for(int i=0;i<4;i++)
#pragma unroll
                for(int j=0;j<4;j++)
                    acc[i][j] = fmaf(aa[i], bb_[j], acc[i][j]);
        }
        __syncthreads();
    }
#pragma unroll
    for(int i=0;i<4;i++){
        int gr = row0 + ty*4 + i;
        if(gr>=M) continue;
#pragma unroll
        for(int j=0;j<4;j++){
            int gc = col0 + tx*4 + j;
            if(gc>=N) continue;
            float v = acc[i][j] + bias[gc];
            if(RESID) v += Rm[(size_t)gr*N+gc];
            C[(size_t)gr*N+gc] = v;
        }
    }
}

// --------------------------- spline kernels --------------------------------

// block per row, 320 threads (275 active). precomputed per-feature knots.
__global__ __launch_bounds__(320)
void ident_spline_kernel(const float* __restrict__ z2, const float* __restrict__ knots,
                         int layer, float* __restrict__ identb,
                         float* __restrict__ znext, float* __restrict__ lq){
    int row = blockIdx.x; int tid = threadIdx.x;
    float ldv = 0.f;
    if(tid < F_DIM){
        const float* kb = knots + ((size_t)(layer*F_DIM + tid))*43;
        float x = z2[(size_t)row*D_DIM + 2*tid];
        float o, l;
        rqs_inv(x, kb, kb+9, kb+17, kb+26, kb+34, o, l);
        identb[(size_t)row*F_DIM + tid] = o;
        znext[(size_t)row*D_DIM + 2*tid] = o;
        ldv = l;
    }
    __shared__ float sm[5];
    float v = ldv;
#pragma unroll
    for(int o=32;o>0;o>>=1) v += __shfl_down(v, o);
    if((tid&63)==0) sm[tid>>6]=v;
    __syncthreads();
    if(tid==0) lq[row] += sm[0]+sm[1]+sm[2]+sm[3]+sm[4];
}

// block per row (chunk-local), 320 threads; p row staged in LDS.
__global__ __launch_bounds__(320)
void trans_spline_kernel(const float* __restrict__ p, const float* __restrict__ z2,
                         float* __restrict__ znext, float* __restrict__ lq, int row_base){
    __shared__ float pp[OUT_DIM];
    int lrow = blockIdx.x; int row = row_base + lrow;
    int tid = threadIdx.x;
    for(int k=tid; k<OUT_DIM; k+=320) pp[k] = p[(size_t)lrow*OUT_DIM + k];
    __syncthreads();
    float ldv = 0.f;
    if(tid < F_DIM){
        const float* q = &pp[tid*23];
        float uw[8], uh[8];
#pragma unroll
        for(int c=0;c<8;c++){ uw[c] = q[c]*RSQRT_HID; uh[c] = q[8+c]*RSQRT_HID; }
        float cw[9], w[8], ch[9], h[8], d[9];
        knots_from_u(uw, cw, w);
        knots_from_u(uh, ch, h);
        float dend = MIND_C + softplusf(DCONST_C);
        d[0]=dend; d[8]=dend;
#pragma unroll
        for(int c=0;c<7;c++) d[c+1] = MIND_C + softplusf(q[16+c]);
        float x = z2[(size_t)row*D_DIM + 2*tid + 1];
        float o, l;
        rqs_inv(x, cw, w, ch, h, d, o, l);
        znext[(size_t)row*D_DIM + 2*tid + 1] = o;
        ldv = l;
    }
    __shared__ float sm[5];
    float v = ldv;
#pragma unroll
    for(int o=32;o>0;o>>=1) v += __shfl_down(v, o);
    if((tid&63)==0) sm[tid>>6]=v;
    __syncthreads();
    if(tid==0) lq[row] += sm[0]+sm[1]+sm[2]+sm[3]+sm[4];
}

// gaussian base log-prob + constants
__global__ __launch_bounds__(320)
void finalize_kernel(const float* __restrict__ z, const float* __restrict__ loc,
                     const float* __restrict__ lsc, const float* __restrict__ lq,
                     const float* __restrict__ logdiag, float* __restrict__ out){
    int row = blockIdx.x; int tid = threadIdx.x;
    float s = 0.f;
    for(int k=tid; k<D_DIM; k+=320){
        float l = lsc[k];
        float diff = (z[(size_t)row*D_DIM+k]-loc[k])*__expf(-l);
        s += l + 0.5f*diff*diff;
    }
    __shared__ float sm[5];
#pragma unroll
    for(int o=32;o>0;o>>=1) s += __shfl_down(s, o);
    if((tid&63)==0) sm[tid>>6]=s;
    __syncthreads();
    if(tid==0){
        float tot = sm[0]+sm[1]+sm[2]+sm[3]+sm[4];
        out[row] = lq[row] + logdiag[0] - 275.f*1.8378770664f - tot;
    }
}

// ---------------------------------------------------------------------------

extern "C" void kernel_launch(void* const* d_in, const int* in_sizes, int n_in,
                              void* d_out, int out_size, void* d_ws, size_t ws_size,
                              hipStream_t stream){
    const float* x        = (const float*)d_in[0];
    const float* loc      = (const float*)d_in[1];
    const float* lsc      = (const float*)d_in[2];
    const float* Wi       = (const float*)d_in[3];
    const float* bi       = (const float*)d_in[4];
    const float* Wb       = (const float*)d_in[5];
    const float* bb       = (const float*)d_in[6];
    const float* Wo       = (const float*)d_in[7];
    const float* bo       = (const float*)d_in[8];
    const float* uw_u     = (const float*)d_in[9];
    const float* uh_u     = (const float*)d_in[10];
    const float* ud_u     = (const float*)d_in[11];
    const float* lu_lower = (const float*)d_in[12];
    const float* lu_upper = (const float*)d_in[13];
    const float* lu_ud    = (const float*)d_in[14];
    const float* lu_b     = (const float*)d_in[15];
    const int*   perms    = (const int*)d_in[16];
    float* out = (float*)d_out;

    // workspace layout (floats)
    float* w = (float*)d_ws;
    float* lq      = w; w += 4096;
    float* logdiag = w; w += 64;
    float* knots   = w; w += 35520;                    // 3*275*43 = 35475
    float* Ap      = w; w += 302528;                   // 550*550
    float* z2      = w; w += (size_t)B_ROWS*D_DIM;
    float* zb0     = w; w += (size_t)B_ROWS*D_DIM;
    float* zb1     = w; w += (size_t)B_ROWS*D_DIM;
    float* identb  = w; w += (size_t)B_ROWS*F_DIM;
    float* tbuf    = w; w += (size_t)B_ROWS*HID_DIM;
    float* rbuf    = w; w += (size_t)B_ROWS*HID_DIM;
    float* pbuf    = w; w += (size_t)CHUNK_ROWS*OUT_DIM;

    hipMemsetAsync(lq, 0, B_ROWS*sizeof(float), stream);
    build_knots_kernel<<<dim3((3*F_DIM+255)/256), dim3(256), 0, stream>>>(uw_u, uh_u, ud_u, knots);
    logdiag_kernel<<<dim3(1), dim3(256), 0, stream>>>(lu_ud, logdiag);

    const float* zcur = x;
    float* zb[2] = {zb0, zb1};
    int zi = 0;
    dim3 thr(16,16);

    for(int it=0; it<3; ++it){
        int i = 2 - it;
        const float* Wbl = Wb + (size_t)i*4*HID_DIM*HID_DIM;
        const float* bbl = bb + (size_t)i*4*HID_DIM;

        build_A_kernel<<<dim3((D_DIM+255)/256, D_DIM), dim3(256), 0, stream>>>(
            lu_lower + (size_t)i*D_DIM*D_DIM, lu_upper + (size_t)i*D_DIM*D_DIM,
            lu_ud + (size_t)i*D_DIM, perms + (size_t)i*D_DIM, Ap);

        // z2 = zcur @ Ap^T + lu_b_i   (M=4096, N=550, K=550)
        gemm64<0,0,1><<<dim3((D_DIM+63)/64, B_ROWS/64), thr, 0, stream>>>(
            zcur, Ap, lu_b + (size_t)i*D_DIM, nullptr, z2, B_ROWS, D_DIM, D_DIM);

        ident_spline_kernel<<<dim3(B_ROWS), dim3(320), 0, stream>>>(
            z2, knots, i, identb, zb[zi], lq);

        // resnet
        gemm64<0,0,0><<<dim3(2, B_ROWS/64), thr, 0, stream>>>(
            identb, Wi + (size_t)i*F_DIM*HID_DIM, bi + (size_t)i*HID_DIM, nullptr,
            tbuf, B_ROWS, HID_DIM, F_DIM);
        gemm64<1,0,0><<<dim3(2, B_ROWS/64), thr, 0, stream>>>(
            tbuf, Wbl + 0*HID_DIM*HID_DIM, bbl + 0*HID_DIM, nullptr,
            rbuf, B_ROWS, HID_DIM, HID_DIM);
        gemm64<1,1,0><<<dim3(2, B_ROWS/64), thr, 0, stream>>>(
            rbuf, Wbl + 1*HID_DIM*HID_DIM, bbl + 1*HID_DIM, tbuf,
            tbuf, B_ROWS, HID_DIM, HID_DIM);
        gemm64<1,0,0><<<dim3(2, B_ROWS/64), thr, 0, stream>>>(
            tbuf, Wbl + 2*HID_DIM*HID_DIM, bbl + 2*HID_DIM, nullptr,
            rbuf, B_ROWS, HID_DIM, HID_DIM);
        gemm64<1,1,0><<<dim3(2, B_ROWS/64), thr, 0, stream>>>(
            rbuf, Wbl + 3*HID_DIM*HID_DIM, bbl + 3*HID_DIM, tbuf,
            tbuf, B_ROWS, HID_DIM, HID_DIM);

        // p (chunked) + conditional spline
        for(int c=0; c<B_ROWS/CHUNK_ROWS; ++c){
            gemm64<0,0,0><<<dim3((OUT_DIM+63)/64, CHUNK_ROWS/64), thr, 0, stream>>>(
                tbuf + (size_t)c*CHUNK_ROWS*HID_DIM, Wo + (size_t)i*HID_DIM*OUT_DIM,
                bo + (size_t)i*OUT_DIM, nullptr, pbuf, CHUNK_ROWS, OUT_DIM, HID_DIM);
            trans_spline_kernel<<<dim3(CHUNK_ROWS), dim3(320), 0, stream>>>(
                pbuf, z2, zb[zi], lq, c*CHUNK_ROWS);
        }

        zcur = zb[zi];
        zi ^= 1;
    }

    finalize_kernel<<<dim3(B_ROWS), dim3(320), 0, stream>>>(
        zcur, loc, lsc, lq, logdiag, out);
}

// Round 2
// 1936.744 us; speedup vs baseline: 1.1047x; 1.1047x over previous
//
#include <hip/hip_runtime.h>

// ---------------------------------------------------------------------------
// DensityEstimator: 3-layer neural spline flow inverse log-prob, fp32.
//
// R1 change: build_A via dense L / perm-folded-U + tiled gemm (was a
// latency-bound serial triangular kernel, ~200us x3 -> ~20us x3).
// ---------------------------------------------------------------------------

#define D_DIM 550
#define F_DIM 275
#define HID_DIM 128
#define OUT_DIM 6325   // F*(3*NB-1)
#define B_ROWS 4096
#define NBINS 8
#define TB_C 3.0f
#define MINB_C 0.001f
#define MIND_C 0.001f
#define DCONST_C 0.53974233f          // log(exp(0.999)-1)
#define LUEPS_C 0.001f
#define RSQRT_HID 0.08838834764831845f // 1/sqrt(128)
#define CHUNK_ROWS 1024

__device__ __forceinline__ float softplusf(float x){
    return fmaxf(x, 0.f) + log1pf(__expf(-fabsf(x)));
}

// widths/cumknots from 8 unnormalized params (softmax -> affine -> cumsum)
__device__ __forceinline__ void knots_from_u(const float* u, float* c, float* w){
    float m = u[0];
#pragma unroll
    for(int k=1;k<NBINS;k++) m = fmaxf(m, u[k]);
    float e[NBINS]; float s = 0.f;
#pragma unroll
    for(int k=0;k<NBINS;k++){ e[k] = __expf(u[k]-m); s += e[k]; }
    float inv = 1.f/s;
    float cum = 0.f;
    c[0] = -TB_C;
#pragma unroll
    for(int k=0;k<NBINS;k++){
        float v = MINB_C + (1.f - MINB_C*(float)NBINS)*e[k]*inv;
        cum += v;
        c[k+1] = 2.f*TB_C*cum - TB_C;
    }
    c[NBINS] = TB_C;  // endpoint forced (matches reference .set)
#pragma unroll
    for(int k=0;k<NBINS;k++) w[k] = c[k+1]-c[k];
}

// inverse rational-quadratic spline, one scalar. cw/w/ch/h/d: 9/8/9/8/9 entries.
__device__ __forceinline__ void rqs_inv(float x,
                                        const float* cw, const float* w,
                                        const float* ch, const float* h,
                                        const float* d,
                                        float& out, float& ld){
    bool inside = (x >= -TB_C) && (x <= TB_C);
    float xi = fminf(fmaxf(x, -TB_C), TB_C);
    int idx = 0;
#pragma unroll
    for(int j=1;j<NBINS;j++) idx += (xi >= ch[j]) ? 1 : 0;
    float icw=cw[0], iw=w[0], ich=ch[0], ih=h[0], d0=d[0], d1=d[1];
#pragma unroll
    for(int j=1;j<NBINS;j++){
        if(idx==j){ icw=cw[j]; iw=w[j]; ich=ch[j]; ih=h[j]; d0=d[j]; d1=d[j+1]; }
    }
    float delta = ih/iw;
    float t  = xi - ich;
    float s  = d0 + d1 - 2.f*delta;
    float a  = t*s + ih*(delta - d0);
    float b  = ih*d0 - t*s;
    float c  = -delta*t;
    float disc = b*b - 4.f*a*c;
    float root = 2.f*c / (-b - sqrtf(fmaxf(disc, 0.f)));
    float o  = root*iw + icw;
    float tm = root*(1.f-root);
    float den  = delta + s*tm;
    float dnum = delta*delta*(d1*root*root + 2.f*delta*tm + d0*(1.f-root)*(1.f-root));
    float l = 2.f*__logf(den) - __logf(dnum);
    out = inside ? o : x;
    ld  = inside ? l : 0.f;
}

// --------------------------- small setup kernels ---------------------------

// per (layer,feature) unconditional spline knots: [3*F][43]
// layout: cw[0..8], w[9..16], ch[17..25], h[26..33], d[34..42]
__global__ void build_knots_kernel(const float* __restrict__ uw_u,
                                   const float* __restrict__ uh_u,
                                   const float* __restrict__ ud_u,
                                   float* __restrict__ knots){
    int g = blockIdx.x*blockDim.x + threadIdx.x;
    if(g >= 3*F_DIM) return;
    float* kb = knots + (size_t)g*43;
    float c[9], w[8];
    knots_from_u(uw_u + (size_t)g*8, c, w);
#pragma unroll
    for(int k=0;k<9;k++) kb[k]=c[k];
#pragma unroll
    for(int k=0;k<8;k++) kb[9+k]=w[k];
    knots_from_u(uh_u + (size_t)g*8, c, w);
#pragma unroll
    for(int k=0;k<9;k++) kb[17+k]=c[k];
#pragma unroll
    for(int k=0;k<8;k++) kb[26+k]=w[k];
    float dend = MIND_C + softplusf(DCONST_C);
    kb[34]=dend; kb[42]=dend;
    const float* ud = ud_u + (size_t)g*7;
#pragma unroll
    for(int k=0;k<7;k++) kb[35+k] = MIND_C + softplusf(ud[k]);
}

// scalar: sum over all 3 layers of sum(log(softplus(lu_ud)+eps))
__global__ void logdiag_kernel(const float* __restrict__ lu_ud, float* __restrict__ outv){
    int tid = threadIdx.x;
    float s = 0.f;
    for(int k=tid; k<3*D_DIM; k+=256) s += __logf(softplusf(lu_ud[k]) + LUEPS_C);
#pragma unroll
    for(int o=32;o>0;o>>=1) s += __shfl_down(s, o);
    __shared__ float sm[4];
    if((tid&63)==0) sm[tid>>6]=s;
    __syncthreads();
    if(tid==0) outv[0] = sm[0]+sm[1]+sm[2]+sm[3];
}

// Dense L (unit lower) and perm-column-folded dense U:
//   Lm[j][k] = j>k ? lower[j][k] : (j==k ? 1 : 0)
//   Up[j][perm[k]] = j<k ? upper[j][k] : (j==k ? softplus(ud[k])+eps : 0)
// Then Ap = Lm @ Up has columns already scattered by perm.
__global__ void build_LU_kernel(const float* __restrict__ lower,
                                const float* __restrict__ upper,
                                const float* __restrict__ ud,
                                const int* __restrict__ perm,
                                float* __restrict__ Lm,
                                float* __restrict__ Up){
    int k = blockIdx.x*blockDim.x + threadIdx.x;
    int j = blockIdx.y;
    if(k >= D_DIM) return;
    float lv = (j>k) ? lower[(size_t)j*D_DIM+k] : (j==k ? 1.f : 0.f);
    Lm[(size_t)j*D_DIM+k] = lv;
    float uv;
    if(j<k)       uv = upper[(size_t)j*D_DIM+k];
    else if(j==k) uv = softplusf(ud[k]) + LUEPS_C;
    else          uv = 0.f;
    Up[(size_t)j*D_DIM + perm[k]] = uv;
}

// ------------------------------- gemm --------------------------------------
// C[M,N] = act(A)[M,K] @ B + bias (+ resid).  BT=0: B[K,N].  BT=1: B[N,K] (B^T).
// 64x64 tile, 16x16 threads, 4x4 micro-tile, K-tile 16.
template<int RELU, int RESID, int BT>
__global__ __launch_bounds__(256)
void gemm64(const float* __restrict__ A, const float* __restrict__ Bm,
            const float* __restrict__ bias, const float* __restrict__ Rm,
            float* __restrict__ C, int M, int N, int K){
    __shared__ float As[16][68];  // [k][m], +4 pad keeps 16B-aligned rows
    __shared__ float Bs[16][68];  // [k][n]
    int tx = threadIdx.x, ty = threadIdx.y;
    int tid = ty*16 + tx;
    int row0 = blockIdx.y*64, col0 = blockIdx.x*64;
    float acc[4][4] = {};
    for(int k0=0; k0<K; k0+=16){
        { // A tile: 64 rows x 16 k
            int r = tid>>4, c = tid&15;
#pragma unroll
            for(int i=0;i<4;i++){
                int rr = r + i*16;
                int gr = row0+rr, gc = k0+c;
                float v = (gr<M && gc<K) ? A[(size_t)gr*K+gc] : 0.f;
                if(RELU) v = fmaxf(v, 0.f);
                As[c][rr] = v;
            }
        }
        if(BT==0){ // B tile: 16 k x 64 n, row-major [K][N]
            int kk = tid>>6, c = tid&63;
#pragma unroll
            for(int i=0;i<4;i++){
                int kr = kk + i*4;
                int gk = k0+kr, gc = col0+c;
                Bs[kr][c] = (gk<K && gc<N) ? Bm[(size_t)gk*N+gc] : 0.f;
            }
        } else {   // B^T: B stored [N][K]
            int n = tid>>4, c = tid&15;
#pragma unroll
            for(int i=0;i<4;i++){
                int nn = n + i*16;
                int gn = col0+nn, gk = k0+c;
                Bs[c][nn] = (gn<N && gk<K) ? Bm[(size_t)gn*K+gk] : 0.f;
            }
        }
        __syncthreads();
#pragma unroll
        for(int kk=0;kk<16;kk++){
            float4 av = *(const float4*)&As[kk][ty*4];
            float4 bv = *(const float4*)&Bs[kk][tx*4];
            float aa[4] = {av.x, av.y, av.z, av.w};
            float bb_[4] = {bv.x, bv.y, bv.z, bv.w};
#pragma unroll
            for(int i=0;i<4;i++)
#pragma unroll
                for(int j=0;j<4;j++)
                    acc[i][j] = fmaf(aa[i], bb_[j], acc[i][j]);
        }
        __syncthreads();
    }
#pragma unroll
    for(int i=0;i<4;i++){
        int gr = row0 + ty*4 + i;
        if(gr>=M) continue;
#pragma unroll
        for(int j=0;j<4;j++){
            int gc = col0 + tx*4 + j;
            if(gc>=N) continue;
            float v = acc[i][j] + bias[gc];
            if(RESID) v += Rm[(size_t)gr*N+gc];
            C[(size_t)gr*N+gc] = v;
        }
    }
}

// --------------------------- spline kernels --------------------------------

// block per row, 320 threads (275 active). precomputed per-feature knots.
__global__ __launch_bounds__(320)
void ident_spline_kernel(const float* __restrict__ z2, const float* __restrict__ knots,
                         int layer, float* __restrict__ identb,
                         float* __restrict__ znext, float* __restrict__ lq){
    int row = blockIdx.x; int tid = threadIdx.x;
    float ldv = 0.f;
    if(tid < F_DIM){
        const float* kb = knots + ((size_t)(layer*F_DIM + tid))*43;
        float x = z2[(size_t)row*D_DIM + 2*tid];
        float o, l;
        rqs_inv(x, kb, kb+9, kb+17, kb+26, kb+34, o, l);
        identb[(size_t)row*F_DIM + tid] = o;
        znext[(size_t)row*D_DIM + 2*tid] = o;
        ldv = l;
    }
    __shared__ float sm[5];
    float v = ldv;
#pragma unroll
    for(int o=32;o>0;o>>=1) v += __shfl_down(v, o);
    if((tid&63)==0) sm[tid>>6]=v;
    __syncthreads();
    if(tid==0) lq[row] += sm[0]+sm[1]+sm[2]+sm[3]+sm[4];
}

// block per row (chunk-local), 320 threads; p row staged in LDS.
__global__ __launch_bounds__(320)
void trans_spline_kernel(const float* __restrict__ p, const float* __restrict__ z2,
                         float* __restrict__ znext, float* __restrict__ lq, int row_base){
    __shared__ float pp[OUT_DIM];
    int lrow = blockIdx.x; int row = row_base + lrow;
    int tid = threadIdx.x;
    for(int k=tid; k<OUT_DIM; k+=320) pp[k] = p[(size_t)lrow*OUT_DIM + k];
    __syncthreads();
    float ldv = 0.f;
    if(tid < F_DIM){
        const float* q = &pp[tid*23];
        float uw[8], uh[8];
#pragma unroll
        for(int c=0;c<8;c++){ uw[c] = q[c]*RSQRT_HID; uh[c] = q[8+c]*RSQRT_HID; }
        float cw[9], w[8], ch[9], h[8], d[9];
        knots_from_u(uw, cw, w);
        knots_from_u(uh, ch, h);
        float dend = MIND_C + softplusf(DCONST_C);
        d[0]=dend; d[8]=dend;
#pragma unroll
        for(int c=0;c<7;c++) d[c+1] = MIND_C + softplusf(q[16+c]);
        float x = z2[(size_t)row*D_DIM + 2*tid + 1];
        float o, l;
        rqs_inv(x, cw, w, ch, h, d, o, l);
        znext[(size_t)row*D_DIM + 2*tid + 1] = o;
        ldv = l;
    }
    __shared__ float sm[5];
    float v = ldv;
#pragma unroll
    for(int o=32;o>0;o>>=1) v += __shfl_down(v, o);
    if((tid&63)==0) sm[tid>>6]=v;
    __syncthreads();
    if(tid==0) lq[row] += sm[0]+sm[1]+sm[2]+sm[3]+sm[4];
}

// gaussian base log-prob + constants
__global__ __launch_bounds__(320)
void finalize_kernel(const float* __restrict__ z, const float* __restrict__ loc,
                     const float* __restrict__ lsc, const float* __restrict__ lq,
                     const float* __restrict__ logdiag, float* __restrict__ out){
    int row = blockIdx.x; int tid = threadIdx.x;
    float s = 0.f;
    for(int k=tid; k<D_DIM; k+=320){
        float l = lsc[k];
        float diff = (z[(size_t)row*D_DIM+k]-loc[k])*__expf(-l);
        s += l + 0.5f*diff*diff;
    }
    __shared__ float sm[5];
#pragma unroll
    for(int o=32;o>0;o>>=1) s += __shfl_down(s, o);
    if((tid&63)==0) sm[tid>>6]=s;
    __syncthreads();
    if(tid==0){
        float tot = sm[0]+sm[1]+sm[2]+sm[3]+sm[4];
        out[row] = lq[row] + logdiag[0] - 275.f*1.8378770664f - tot;
    }
}

// ---------------------------------------------------------------------------

extern "C" void kernel_launch(void* const* d_in, const int* in_sizes, int n_in,
                              void* d_out, int out_size, void* d_ws, size_t ws_size,
                              hipStream_t stream){
    const float* x        = (const float*)d_in[0];
    const float* loc      = (const float*)d_in[1];
    const float* lsc      = (const float*)d_in[2];
    const float* Wi       = (const float*)d_in[3];
    const float* bi       = (const float*)d_in[4];
    const float* Wb       = (const float*)d_in[5];
    const float* bb       = (const float*)d_in[6];
    const float* Wo       = (const float*)d_in[7];
    const float* bo       = (const float*)d_in[8];
    const float* uw_u     = (const float*)d_in[9];
    const float* uh_u     = (const float*)d_in[10];
    const float* ud_u     = (const float*)d_in[11];
    const float* lu_lower = (const float*)d_in[12];
    const float* lu_upper = (const float*)d_in[13];
    const float* lu_ud    = (const float*)d_in[14];
    const float* lu_b     = (const float*)d_in[15];
    const int*   perms    = (const int*)d_in[16];
    float* out = (float*)d_out;

    // workspace layout (floats)
    float* w = (float*)d_ws;
    float* lq      = w; w += 4096;
    float* logdiag = w; w += 64;
    float* zbias   = w; w += 576;                      // zeros (gemm bias for A-build)
    float* knots   = w; w += 35520;                    // 3*275*43 = 35475
    float* Lm      = w; w += 302528;                   // 550*550 dense L
    float* Up      = w; w += 302528;                   // 550*550 perm-folded U
    float* Ap      = w; w += 302528;                   // 550*550
    float* z2      = w; w += (size_t)B_ROWS*D_DIM;
    float* zb0     = w; w += (size_t)B_ROWS*D_DIM;
    float* zb1     = w; w += (size_t)B_ROWS*D_DIM;
    float* identb  = w; w += (size_t)B_ROWS*F_DIM;
    float* tbuf    = w; w += (size_t)B_ROWS*HID_DIM;
    float* rbuf    = w; w += (size_t)B_ROWS*HID_DIM;
    float* pbuf    = w; w += (size_t)CHUNK_ROWS*OUT_DIM;

    hipMemsetAsync(lq, 0, B_ROWS*sizeof(float), stream);
    hipMemsetAsync(zbias, 0, 576*sizeof(float), stream);
    build_knots_kernel<<<dim3((3*F_DIM+255)/256), dim3(256), 0, stream>>>(uw_u, uh_u, ud_u, knots);
    logdiag_kernel<<<dim3(1), dim3(256), 0, stream>>>(lu_ud, logdiag);

    const float* zcur = x;
    float* zb[2] = {zb0, zb1};
    int zi = 0;
    dim3 thr(16,16);

    for(int it=0; it<3; ++it){
        int i = 2 - it;
        const float* Wbl = Wb + (size_t)i*4*HID_DIM*HID_DIM;
        const float* bbl = bb + (size_t)i*4*HID_DIM;

        // A = L @ U with perm folded into U's columns, via dense gemm
        build_LU_kernel<<<dim3((D_DIM+255)/256, D_DIM), dim3(256), 0, stream>>>(
            lu_lower + (size_t)i*D_DIM*D_DIM, lu_upper + (size_t)i*D_DIM*D_DIM,
            lu_ud + (size_t)i*D_DIM, perms + (size_t)i*D_DIM, Lm, Up);
        gemm64<0,0,0><<<dim3((D_DIM+63)/64, (D_DIM+63)/64), thr, 0, stream>>>(
            Lm, Up, zbias, nullptr, Ap, D_DIM, D_DIM, D_DIM);

        // z2 = zcur @ Ap^T + lu_b_i   (M=4096, N=550, K=550)
        gemm64<0,0,1><<<dim3((D_DIM+63)/64, B_ROWS/64), thr, 0, stream>>>(
            zcur, Ap, lu_b + (size_t)i*D_DIM, nullptr, z2, B_ROWS, D_DIM, D_DIM);

        ident_spline_kernel<<<dim3(B_ROWS), dim3(320), 0, stream>>>(
            z2, knots, i, identb, zb[zi], lq);

        // resnet
        gemm64<0,0,0><<<dim3(2, B_ROWS/64), thr, 0, stream>>>(
            identb, Wi + (size_t)i*F_DIM*HID_DIM, bi + (size_t)i*HID_DIM, nullptr,
            tbuf, B_ROWS, HID_DIM, F_DIM);
        gemm64<1,0,0><<<dim3(2, B_ROWS/64), thr, 0, stream>>>(
            tbuf, Wbl + 0*HID_DIM*HID_DIM, bbl + 0*HID_DIM, nullptr,
            rbuf, B_ROWS, HID_DIM, HID_DIM);
        gemm64<1,1,0><<<dim3(2, B_ROWS/64), thr, 0, stream>>>(
            rbuf, Wbl + 1*HID_DIM*HID_DIM, bbl + 1*HID_DIM, tbuf,
            tbuf, B_ROWS, HID_DIM, HID_DIM);
        gemm64<1,0,0><<<dim3(2, B_ROWS/64), thr, 0, stream>>>(
            tbuf, Wbl + 2*HID_DIM*HID_DIM, bbl + 2*HID_DIM, nullptr,
            rbuf, B_ROWS, HID_DIM, HID_DIM);
        gemm64<1,1,0><<<dim3(2, B_ROWS/64), thr, 0, stream>>>(
            rbuf, Wbl + 3*HID_DIM*HID_DIM, bbl + 3*HID_DIM, tbuf,
            tbuf, B_ROWS, HID_DIM, HID_DIM);

        // p (chunked) + conditional spline
        for(int c=0; c<B_ROWS/CHUNK_ROWS; ++c){
            gemm64<0,0,0><<<dim3((OUT_DIM+63)/64, CHUNK_ROWS/64), thr, 0, stream>>>(
                tbuf + (size_t)c*CHUNK_ROWS*HID_DIM, Wo + (size_t)i*HID_DIM*OUT_DIM,
                bo + (size_t)i*OUT_DIM, nullptr, pbuf, CHUNK_ROWS, OUT_DIM, HID_DIM);
            trans_spline_kernel<<<dim3(CHUNK_ROWS), dim3(320), 0, stream>>>(
                pbuf, z2, zb[zi], lq, c*CHUNK_ROWS);
        }

        zcur = zb[zi];
        zi ^= 1;
    }

    finalize_kernel<<<dim3(B_ROWS), dim3(320), 0, stream>>>(
        zcur, loc, lsc, lq, logdiag, out);
}

// Round 3
// 1337.305 us; speedup vs baseline: 1.5999x; 1.4482x over previous
//
#include <hip/hip_runtime.h>

// ---------------------------------------------------------------------------
// DensityEstimator: 3-layer neural spline flow inverse log-prob.
// R2: all production gemms (LU z2, resnet, Wo) -> bf16 MFMA 16x16x32,
//     fp32 accumulate. Weights pre-transposed to [n][k] bf16, activations
//     kept in bf16 padded buffers. fp32 gemm64 kept only for A=L@U build.
// ---------------------------------------------------------------------------

#define D_DIM 550
#define D_PAD 576      // K-pad (64-mult) for z dimension
#define N_PAD_A 640    // row-pad (128-mult) of Ap as Bt
#define F_DIM 275
#define F_PAD 320
#define HID_DIM 128
#define OUT_DIM 6325   // F*(3*NB-1)
#define OUT_PAD 6400
#define B_ROWS 4096
#define NBINS 8
#define TB_C 3.0f
#define MINB_C 0.001f
#define MIND_C 0.001f
#define DCONST_C 0.53974233f
#define LUEPS_C 0.001f
#define RSQRT_HID 0.08838834764831845f
#define CHUNK_ROWS 512

typedef unsigned short ushort_t;
typedef __attribute__((ext_vector_type(8))) short short8;
typedef __attribute__((ext_vector_type(8))) unsigned short ushort8;
typedef __attribute__((ext_vector_type(4))) float f32x4;

__device__ __forceinline__ ushort_t f2bf(float f){
    union{float f; unsigned u;} v; v.f = f;
    unsigned r = v.u + 0x7fffu + ((v.u>>16)&1u);
    return (ushort_t)(r>>16);
}
__device__ __forceinline__ float bf2f(ushort_t h){
    union{unsigned u; float f;} v; v.u = ((unsigned)h)<<16;
    return v.f;
}
__device__ __forceinline__ float softplusf(float x){
    return fmaxf(x, 0.f) + log1pf(__expf(-fabsf(x)));
}

__device__ __forceinline__ void knots_from_u(const float* u, float* c, float* w){
    float m = u[0];
#pragma unroll
    for(int k=1;k<NBINS;k++) m = fmaxf(m, u[k]);
    float e[NBINS]; float s = 0.f;
#pragma unroll
    for(int k=0;k<NBINS;k++){ e[k] = __expf(u[k]-m); s += e[k]; }
    float inv = 1.f/s;
    float cum = 0.f;
    c[0] = -TB_C;
#pragma unroll
    for(int k=0;k<NBINS;k++){
        float v = MINB_C + (1.f - MINB_C*(float)NBINS)*e[k]*inv;
        cum += v;
        c[k+1] = 2.f*TB_C*cum - TB_C;
    }
    c[NBINS] = TB_C;
#pragma unroll
    for(int k=0;k<NBINS;k++) w[k] = c[k+1]-c[k];
}

__device__ __forceinline__ void rqs_inv(float x,
                                        const float* cw, const float* w,
                                        const float* ch, const float* h,
                                        const float* d,
                                        float& out, float& ld){
    bool inside = (x >= -TB_C) && (x <= TB_C);
    float xi = fminf(fmaxf(x, -TB_C), TB_C);
    int idx = 0;
#pragma unroll
    for(int j=1;j<NBINS;j++) idx += (xi >= ch[j]) ? 1 : 0;
    float icw=cw[0], iw=w[0], ich=ch[0], ih=h[0], d0=d[0], d1=d[1];
#pragma unroll
    for(int j=1;j<NBINS;j++){
        if(idx==j){ icw=cw[j]; iw=w[j]; ich=ch[j]; ih=h[j]; d0=d[j]; d1=d[j+1]; }
    }
    float delta = ih/iw;
    float t  = xi - ich;
    float s  = d0 + d1 - 2.f*delta;
    float a  = t*s + ih*(delta - d0);
    float b  = ih*d0 - t*s;
    float c  = -delta*t;
    float disc = b*b - 4.f*a*c;
    float root = 2.f*c / (-b - sqrtf(fmaxf(disc, 0.f)));
    float o  = root*iw + icw;
    float tm = root*(1.f-root);
    float den  = delta + s*tm;
    float dnum = delta*delta*(d1*root*root + 2.f*delta*tm + d0*(1.f-root)*(1.f-root));
    float l = 2.f*__logf(den) - __logf(dnum);
    out = inside ? o : x;
    ld  = inside ? l : 0.f;
}

// --------------------------- setup kernels ---------------------------------

__global__ void build_knots_kernel(const float* __restrict__ uw_u,
                                   const float* __restrict__ uh_u,
                                   const float* __restrict__ ud_u,
                                   float* __restrict__ knots){
    int g = blockIdx.x*blockDim.x + threadIdx.x;
    if(g >= 3*F_DIM) return;
    float* kb = knots + (size_t)g*43;
    float c[9], w[8];
    knots_from_u(uw_u + (size_t)g*8, c, w);
#pragma unroll
    for(int k=0;k<9;k++) kb[k]=c[k];
#pragma unroll
    for(int k=0;k<8;k++) kb[9+k]=w[k];
    knots_from_u(uh_u + (size_t)g*8, c, w);
#pragma unroll
    for(int k=0;k<9;k++) kb[17+k]=c[k];
#pragma unroll
    for(int k=0;k<8;k++) kb[26+k]=w[k];
    float dend = MIND_C + softplusf(DCONST_C);
    kb[34]=dend; kb[42]=dend;
    const float* ud = ud_u + (size_t)g*7;
#pragma unroll
    for(int k=0;k<7;k++) kb[35+k] = MIND_C + softplusf(ud[k]);
}

__global__ void logdiag_kernel(const float* __restrict__ lu_ud, float* __restrict__ outv){
    int tid = threadIdx.x;
    float s = 0.f;
    for(int k=tid; k<3*D_DIM; k+=256) s += __logf(softplusf(lu_ud[k]) + LUEPS_C);
#pragma unroll
    for(int o=32;o>0;o>>=1) s += __shfl_down(s, o);
    __shared__ float sm[4];
    if((tid&63)==0) sm[tid>>6]=s;
    __syncthreads();
    if(tid==0) outv[0] = sm[0]+sm[1]+sm[2]+sm[3];
}

__global__ void build_LU_kernel(const float* __restrict__ lower,
                                const float* __restrict__ upper,
                                const float* __restrict__ ud,
                                const int* __restrict__ perm,
                                float* __restrict__ Lm,
                                float* __restrict__ Up){
    int k = blockIdx.x*blockDim.x + threadIdx.x;
    int j = blockIdx.y;
    if(k >= D_DIM) return;
    float lv = (j>k) ? lower[(size_t)j*D_DIM+k] : (j==k ? 1.f : 0.f);
    Lm[(size_t)j*D_DIM+k] = lv;
    float uv;
    if(j<k)       uv = upper[(size_t)j*D_DIM+k];
    else if(j==k) uv = softplusf(ud[k]) + LUEPS_C;
    else          uv = 0.f;
    Up[(size_t)j*D_DIM + perm[k]] = uv;
}

// fp32 [M][K] -> bf16 [Mpad][Kpad], zero-padded
__global__ void convert_pad(const float* __restrict__ in, ushort_t* __restrict__ out,
                            int M, int K, int Mpad, int Kpad){
    int idx = blockIdx.x*256 + threadIdx.x;
    if(idx >= Mpad*Kpad) return;
    int r = idx / Kpad, c = idx - r*Kpad;
    float v = (r<M && c<K) ? in[(size_t)r*K+c] : 0.f;
    out[idx] = f2bf(v);
}

// fp32 in[K][N] -> bf16 out[Npad][Kpad] (transpose), zero-padded. block 32x8.
__global__ void transpose_convert(const float* __restrict__ in, ushort_t* __restrict__ out,
                                  int K, int N, int Kpad, int Npad){
    __shared__ float t[32][33];
    int kb = blockIdx.x*32, nb = blockIdx.y*32;
    int tx = threadIdx.x, ty = threadIdx.y;
#pragma unroll
    for(int i=0;i<32;i+=8){
        int k = kb+ty+i, n = nb+tx;
        t[ty+i][tx] = (k<K && n<N) ? in[(size_t)k*N+n] : 0.f;
    }
    __syncthreads();
#pragma unroll
    for(int i=0;i<32;i+=8){
        int n = nb+ty+i, k = kb+tx;
        if(n<Npad && k<Kpad) out[(size_t)n*Kpad+k] = f2bf(t[tx][ty+i]);
    }
}

// zero the pad columns [550..576) of the two bf16 z buffers
__global__ void zero_pad_cols(ushort_t* __restrict__ z0, ushort_t* __restrict__ z1){
    int idx = blockIdx.x*256 + threadIdx.x;
    if(idx >= B_ROWS*(D_PAD-D_DIM)) return;
    int r = idx/(D_PAD-D_DIM), c = D_DIM + idx%(D_PAD-D_DIM);
    z0[(size_t)r*D_PAD+c]=0; z1[(size_t)r*D_PAD+c]=0;
}

// ------------------------- fp32 gemm (A-build only) ------------------------
template<int RELU, int RESID, int BT>
__global__ __launch_bounds__(256)
void gemm64(const float* __restrict__ A, const float* __restrict__ Bm,
            const float* __restrict__ bias, const float* __restrict__ Rm,
            float* __restrict__ C, int M, int N, int K){
    __shared__ float As[16][68];
    __shared__ float Bs[16][68];
    int tx = threadIdx.x, ty = threadIdx.y;
    int tid = ty*16 + tx;
    int row0 = blockIdx.y*64, col0 = blockIdx.x*64;
    float acc[4][4] = {};
    for(int k0=0; k0<K; k0+=16){
        {
            int r = tid>>4, c = tid&15;
#pragma unroll
            for(int i=0;i<4;i++){
                int rr = r + i*16;
                int gr = row0+rr, gc = k0+c;
                float v = (gr<M && gc<K) ? A[(size_t)gr*K+gc] : 0.f;
                if(RELU) v = fmaxf(v, 0.f);
                As[c][rr] = v;
            }
        }
        if(BT==0){
            int kk = tid>>6, c = tid&63;
#pragma unroll
            for(int i=0;i<4;i++){
                int kr = kk + i*4;
                int gk = k0+kr, gc = col0+c;
                Bs[kr][c] = (gk<K && gc<N) ? Bm[(size_t)gk*N+gc] : 0.f;
            }
        } else {
            int n = tid>>4, c = tid&15;
#pragma unroll
            for(int i=0;i<4;i++){
                int nn = n + i*16;
                int gn = col0+nn, gk = k0+c;
                Bs[c][nn] = (gn<N && gk<K) ? Bm[(size_t)gn*K+gk] : 0.f;
            }
        }
        __syncthreads();
#pragma unroll
        for(int kk=0;kk<16;kk++){
            float4 av = *(const float4*)&As[kk][ty*4];
            float4 bv = *(const float4*)&Bs[kk][tx*4];
            float aa[4] = {av.x, av.y, av.z, av.w};
            float bb_[4] = {bv.x, bv.y, bv.z, bv.w};
#pragma unroll
            for(int i=0;i<4;i++)
#pragma unroll
                for(int j=0;j<4;j++)
                    acc[i][j] = fmaf(aa[i], bb_[j], acc[i][j]);
        }
        __syncthreads();
    }
#pragma unroll
    for(int i=0;i<4;i++){
        int gr = row0 + ty*4 + i;
        if(gr>=M) continue;
#pragma unroll
        for(int j=0;j<4;j++){
            int gc = col0 + tx*4 + j;
            if(gc>=N) continue;
            float v = acc[i][j] + bias[gc];
            if(RESID) v += Rm[(size_t)gr*N+gc];
            C[(size_t)gr*N+gc] = v;
        }
    }
}

// ------------------------------ bf16 MFMA gemm -----------------------------
// A: bf16 [M][Kpad] (M mult of 128 per grid, rows fully allocated)
// Bt: bf16 [Npad][Kpad], Npad = gridDim.x*128
// C: [M][N] fp32 (OUTBF=0) or bf16 (OUTBF=1); bias fp32 [N]; Rm bf16 [M][N]
template<int RELU, int RESID, int OUTBF>
__global__ __launch_bounds__(256)
void gemm_mfma(const ushort_t* __restrict__ A, const ushort_t* __restrict__ Bt,
               const float* __restrict__ bias, const ushort_t* __restrict__ Rm,
               void* __restrict__ Cv, int M, int N, int Kpad){
    __shared__ ushort_t As[128][72];
    __shared__ ushort_t Bs[128][72];
    int tid = threadIdx.x;
    int row0 = blockIdx.y*128, col0 = blockIdx.x*128;
    int wave = tid>>6, lane = tid&63;
    int wm = wave&1, wn = wave>>1;
    int lm = lane&15, quad = lane>>4;
    f32x4 acc[4][4] = {};
    for(int k0=0; k0<Kpad; k0+=64){
#pragma unroll
        for(int it=0; it<4; it++){
            int c = tid + it*256;
            int r = c>>3, c8 = (c&7)*8;
            ushort8 va = *(const ushort8*)(A + (size_t)(row0+r)*Kpad + k0 + c8);
            if(RELU){
#pragma unroll
                for(int e=0;e<8;e++) va[e] = (va[e]&0x8000u) ? (unsigned short)0 : va[e];
            }
            *(ushort8*)&As[r][c8] = va;
            ushort8 vb = *(const ushort8*)(Bt + (size_t)(col0+r)*Kpad + k0 + c8);
            *(ushort8*)&Bs[r][c8] = vb;
        }
        __syncthreads();
#pragma unroll
        for(int ks=0; ks<2; ks++){
            short8 af[4], bfr[4];
#pragma unroll
            for(int i=0;i<4;i++){
                af[i]  = *(const short8*)&As[wm*64 + i*16 + lm][ks*32 + quad*8];
                bfr[i] = *(const short8*)&Bs[wn*64 + i*16 + lm][ks*32 + quad*8];
            }
#pragma unroll
            for(int i=0;i<4;i++)
#pragma unroll
                for(int j=0;j<4;j++)
                    acc[i][j] = __builtin_amdgcn_mfma_f32_16x16x32_bf16(af[i], bfr[j], acc[i][j], 0, 0, 0);
        }
        __syncthreads();
    }
#pragma unroll
    for(int i=0;i<4;i++){
        int rbase = row0 + wm*64 + i*16 + quad*4;
#pragma unroll
        for(int j=0;j<4;j++){
            int gc = col0 + wn*64 + j*16 + lm;
            if(gc >= N) continue;
            float bv = bias[gc];
#pragma unroll
            for(int r=0;r<4;r++){
                int gr = rbase + r;
                float v = acc[i][j][r] + bv;
                if(RESID) v += bf2f(Rm[(size_t)gr*N+gc]);
                if(OUTBF) ((ushort_t*)Cv)[(size_t)gr*N+gc] = f2bf(v);
                else      ((float*)Cv)[(size_t)gr*N+gc] = v;
            }
        }
    }
}

// --------------------------- spline kernels --------------------------------

__global__ __launch_bounds__(320)
void ident_spline_kernel(const float* __restrict__ z2, const float* __restrict__ knots,
                         int layer, ushort_t* __restrict__ identb,
                         float* __restrict__ znf, ushort_t* __restrict__ znb,
                         float* __restrict__ lq){
    int row = blockIdx.x; int tid = threadIdx.x;
    float ldv = 0.f;
    if(tid < F_DIM){
        const float* kb = knots + ((size_t)(layer*F_DIM + tid))*43;
        float x = z2[(size_t)row*D_DIM + 2*tid];
        float o, l;
        rqs_inv(x, kb, kb+9, kb+17, kb+26, kb+34, o, l);
        identb[(size_t)row*F_PAD + tid] = f2bf(o);
        znf[(size_t)row*D_DIM + 2*tid] = o;
        znb[(size_t)row*D_PAD + 2*tid] = f2bf(o);
        ldv = l;
    } else {
        identb[(size_t)row*F_PAD + tid] = 0;  // zero pad cols 275..319
    }
    __shared__ float sm[5];
    float v = ldv;
#pragma unroll
    for(int o=32;o>0;o>>=1) v += __shfl_down(v, o);
    if((tid&63)==0) sm[tid>>6]=v;
    __syncthreads();
    if(tid==0) lq[row] += sm[0]+sm[1]+sm[2]+sm[3]+sm[4];
}

__global__ __launch_bounds__(320)
void trans_spline_kernel(const float* __restrict__ p, const float* __restrict__ z2,
                         float* __restrict__ znf, ushort_t* __restrict__ znb,
                         float* __restrict__ lq, int row_base){
    __shared__ float pp[OUT_DIM];
    int lrow = blockIdx.x; int row = row_base + lrow;
    int tid = threadIdx.x;
    for(int k=tid; k<OUT_DIM; k+=320) pp[k] = p[(size_t)lrow*OUT_DIM + k];
    __syncthreads();
    float ldv = 0.f;
    if(tid < F_DIM){
        const float* q = &pp[tid*23];
        float uw[8], uh[8];
#pragma unroll
        for(int c=0;c<8;c++){ uw[c] = q[c]*RSQRT_HID; uh[c] = q[8+c]*RSQRT_HID; }
        float cw[9], w[8], ch[9], h[8], d[9];
        knots_from_u(uw, cw, w);
        knots_from_u(uh, ch, h);
        float dend = MIND_C + softplusf(DCONST_C);
        d[0]=dend; d[8]=dend;
#pragma unroll
        for(int c=0;c<7;c++) d[c+1] = MIND_C + softplusf(q[16+c]);
        float x = z2[(size_t)row*D_DIM + 2*tid + 1];
        float o, l;
        rqs_inv(x, cw, w, ch, h, d, o, l);
        znf[(size_t)row*D_DIM + 2*tid + 1] = o;
        znb[(size_t)row*D_PAD + 2*tid + 1] = f2bf(o);
        ldv = l;
    }
    __shared__ float sm[5];
    float v = ldv;
#pragma unroll
    for(int o=32;o>0;o>>=1) v += __shfl_down(v, o);
    if((tid&63)==0) sm[tid>>6]=v;
    __syncthreads();
    if(tid==0) lq[row] += sm[0]+sm[1]+sm[2]+sm[3]+sm[4];
}

__global__ __launch_bounds__(320)
void finalize_kernel(const float* __restrict__ z, const float* __restrict__ loc,
                     const float* __restrict__ lsc, const float* __restrict__ lq,
                     const float* __restrict__ logdiag, float* __restrict__ out){
    int row = blockIdx.x; int tid = threadIdx.x;
    float s = 0.f;
    for(int k=tid; k<D_DIM; k+=320){
        float l = lsc[k];
        float diff = (z[(size_t)row*D_DIM+k]-loc[k])*__expf(-l);
        s += l + 0.5f*diff*diff;
    }
    __shared__ float sm[5];
#pragma unroll
    for(int o=32;o>0;o>>=1) s += __shfl_down(s, o);
    if((tid&63)==0) sm[tid>>6]=s;
    __syncthreads();
    if(tid==0){
        float tot = sm[0]+sm[1]+sm[2]+sm[3]+sm[4];
        out[row] = lq[row] + logdiag[0] - 275.f*1.8378770664f - tot;
    }
}

// ---------------------------------------------------------------------------

extern "C" void kernel_launch(void* const* d_in, const int* in_sizes, int n_in,
                              void* d_out, int out_size, void* d_ws, size_t ws_size,
                              hipStream_t stream){
    const float* x        = (const float*)d_in[0];
    const float* loc      = (const float*)d_in[1];
    const float* lsc      = (const float*)d_in[2];
    const float* Wi       = (const float*)d_in[3];
    const float* bi       = (const float*)d_in[4];
    const float* Wb       = (const float*)d_in[5];
    const float* bb       = (const float*)d_in[6];
    const float* Wo       = (const float*)d_in[7];
    const float* bo       = (const float*)d_in[8];
    const float* uw_u     = (const float*)d_in[9];
    const float* uh_u     = (const float*)d_in[10];
    const float* ud_u     = (const float*)d_in[11];
    const float* lu_lower = (const float*)d_in[12];
    const float* lu_upper = (const float*)d_in[13];
    const float* lu_ud    = (const float*)d_in[14];
    const float* lu_b     = (const float*)d_in[15];
    const int*   perms    = (const int*)d_in[16];
    float* out = (float*)d_out;

    char* base = (char*)d_ws;
    size_t off = 0;
    auto alloc = [&](size_t bytes)->char*{
        char* p = base + off;
        off += (bytes + 255) & ~(size_t)255;
        return p;
    };
    float* lq      = (float*)alloc(B_ROWS*4);
    float* zbias   = (float*)alloc(D_PAD*4);
    float* logdiag = (float*)alloc(64*4);
    float* knots   = (float*)alloc((size_t)3*F_DIM*43*4);
    float* Lm      = (float*)alloc((size_t)D_DIM*D_DIM*4);
    float* Up      = (float*)alloc((size_t)D_DIM*D_DIM*4);
    float* Ap      = (float*)alloc((size_t)D_DIM*D_DIM*4);
    float* z2      = (float*)alloc((size_t)B_ROWS*D_DIM*4);
    float* zf0     = (float*)alloc((size_t)B_ROWS*D_DIM*4);
    float* zf1     = (float*)alloc((size_t)B_ROWS*D_DIM*4);
    float* pbuf    = (float*)alloc((size_t)CHUNK_ROWS*OUT_DIM*4);
    ushort_t* xb   = (ushort_t*)alloc((size_t)B_ROWS*D_PAD*2);
    ushort_t* zbf0 = (ushort_t*)alloc((size_t)B_ROWS*D_PAD*2);
    ushort_t* zbf1 = (ushort_t*)alloc((size_t)B_ROWS*D_PAD*2);
    ushort_t* Apb  = (ushort_t*)alloc((size_t)N_PAD_A*D_PAD*2);
    ushort_t* identb=(ushort_t*)alloc((size_t)B_ROWS*F_PAD*2);
    ushort_t* tb   = (ushort_t*)alloc((size_t)B_ROWS*HID_DIM*2);
    ushort_t* rb   = (ushort_t*)alloc((size_t)B_ROWS*HID_DIM*2);
    ushort_t* WiT  = (ushort_t*)alloc((size_t)HID_DIM*F_PAD*2);
    ushort_t* WbT  = (ushort_t*)alloc((size_t)4*HID_DIM*HID_DIM*2);
    ushort_t* WoT  = (ushort_t*)alloc((size_t)OUT_PAD*HID_DIM*2);

    hipMemsetAsync(lq, 0, B_ROWS*sizeof(float), stream);
    hipMemsetAsync(zbias, 0, D_PAD*sizeof(float), stream);
    build_knots_kernel<<<dim3((3*F_DIM+255)/256), dim3(256), 0, stream>>>(uw_u, uh_u, ud_u, knots);
    logdiag_kernel<<<dim3(1), dim3(256), 0, stream>>>(lu_ud, logdiag);
    zero_pad_cols<<<dim3((B_ROWS*(D_PAD-D_DIM)+255)/256), dim3(256), 0, stream>>>(zbf0, zbf1);
    convert_pad<<<dim3((B_ROWS*D_PAD+255)/256), dim3(256), 0, stream>>>(
        x, xb, B_ROWS, D_DIM, B_ROWS, D_PAD);

    const ushort_t* zcur_b = xb;
    const float* zcur_f = nullptr;
    ushort_t* zbf[2] = {zbf0, zbf1};
    float* zf[2] = {zf0, zf1};
    int zi = 0;
    dim3 thr(16,16);
    dim3 tthr(32,8);

    for(int it=0; it<3; ++it){
        int i = 2 - it;
        const float* Wbl = Wb + (size_t)i*4*HID_DIM*HID_DIM;
        const float* bbl = bb + (size_t)i*4*HID_DIM;

        // ---- A = L@U (perm folded), fp32, then convert to padded bf16 Bt
        build_LU_kernel<<<dim3((D_DIM+255)/256, D_DIM), dim3(256), 0, stream>>>(
            lu_lower + (size_t)i*D_DIM*D_DIM, lu_upper + (size_t)i*D_DIM*D_DIM,
            lu_ud + (size_t)i*D_DIM, perms + (size_t)i*D_DIM, Lm, Up);
        gemm64<0,0,0><<<dim3((D_DIM+63)/64, (D_DIM+63)/64), thr, 0, stream>>>(
            Lm, Up, zbias, nullptr, Ap, D_DIM, D_DIM, D_DIM);
        convert_pad<<<dim3((N_PAD_A*D_PAD+255)/256), dim3(256), 0, stream>>>(
            Ap, Apb, D_DIM, D_DIM, N_PAD_A, D_PAD);

        // ---- weight transposes (bf16 [n][k])
        transpose_convert<<<dim3(F_PAD/32, HID_DIM/32), tthr, 0, stream>>>(
            Wi + (size_t)i*F_DIM*HID_DIM, WiT, F_DIM, HID_DIM, F_PAD, HID_DIM);
        for(int j=0;j<4;j++)
            transpose_convert<<<dim3(HID_DIM/32, HID_DIM/32), tthr, 0, stream>>>(
                Wbl + (size_t)j*HID_DIM*HID_DIM, WbT + (size_t)j*HID_DIM*HID_DIM,
                HID_DIM, HID_DIM, HID_DIM, HID_DIM);
        transpose_convert<<<dim3(HID_DIM/32, OUT_PAD/32), tthr, 0, stream>>>(
            Wo + (size_t)i*HID_DIM*OUT_DIM, WoT, HID_DIM, OUT_DIM, HID_DIM, OUT_PAD);

        // ---- z2 = z @ Ap^T + lu_b  (MFMA)
        gemm_mfma<0,0,0><<<dim3(N_PAD_A/128, B_ROWS/128), dim3(256), 0, stream>>>(
            zcur_b, Apb, lu_b + (size_t)i*D_DIM, nullptr, z2, B_ROWS, D_DIM, D_PAD);

        ident_spline_kernel<<<dim3(B_ROWS), dim3(320), 0, stream>>>(
            z2, knots, i, identb, zf[zi], zbf[zi], lq);

        // ---- resnet (MFMA, bf16 intermediates)
        gemm_mfma<0,0,1><<<dim3(1, B_ROWS/128), dim3(256), 0, stream>>>(
            identb, WiT, bi + (size_t)i*HID_DIM, nullptr, tb, B_ROWS, HID_DIM, F_PAD);
        gemm_mfma<1,0,1><<<dim3(1, B_ROWS/128), dim3(256), 0, stream>>>(
            tb, WbT + 0*HID_DIM*HID_DIM, bbl + 0*HID_DIM, nullptr, rb, B_ROWS, HID_DIM, HID_DIM);
        gemm_mfma<1,1,1><<<dim3(1, B_ROWS/128), dim3(256), 0, stream>>>(
            rb, WbT + 1*HID_DIM*HID_DIM, bbl + 1*HID_DIM, tb, tb, B_ROWS, HID_DIM, HID_DIM);
        gemm_mfma<1,0,1><<<dim3(1, B_ROWS/128), dim3(256), 0, stream>>>(
            tb, WbT + 2*HID_DIM*HID_DIM, bbl + 2*HID_DIM, nullptr, rb, B_ROWS, HID_DIM, HID_DIM);
        gemm_mfma<1,1,1><<<dim3(1, B_ROWS/128), dim3(256), 0, stream>>>(
            rb, WbT + 3*HID_DIM*HID_DIM, bbl + 3*HID_DIM, tb, tb, B_ROWS, HID_DIM, HID_DIM);

        // ---- p (chunked) + conditional spline
        for(int c=0; c<B_ROWS/CHUNK_ROWS; ++c){
            gemm_mfma<0,0,0><<<dim3(OUT_PAD/128, CHUNK_ROWS/128), dim3(256), 0, stream>>>(
                tb + (size_t)c*CHUNK_ROWS*HID_DIM, WoT, bo + (size_t)i*OUT_DIM, nullptr,
                pbuf, CHUNK_ROWS, OUT_DIM, HID_DIM);
            trans_spline_kernel<<<dim3(CHUNK_ROWS), dim3(320), 0, stream>>>(
                pbuf, z2, zf[zi], zbf[zi], lq, c*CHUNK_ROWS);
        }

        zcur_b = zbf[zi];
        zcur_f = zf[zi];
        zi ^= 1;
    }

    finalize_kernel<<<dim3(B_ROWS), dim3(320), 0, stream>>>(
        zcur_f, loc, lsc, lq, logdiag, out);
}

// Round 4
// 859.298 us; speedup vs baseline: 2.4899x; 1.5563x over previous
//
#include <hip/hip_runtime.h>

// ---------------------------------------------------------------------------
// DensityEstimator: 3-layer neural spline flow inverse log-prob.
// R3: A = L@U build moved to bf16 MFMA (was fp32 gemm64 at 103us, occupancy
//     3% — latency-bound 81-block grid). pbuf -> bf16, CHUNK 512 -> 1024.
// ---------------------------------------------------------------------------

#define D_DIM 550
#define D_PAD 576      // K-pad (64-mult) for z dimension
#define N_PAD_A 640    // row-pad (128-mult) of Ap as Bt
#define F_DIM 275
#define F_PAD 320
#define HID_DIM 128
#define OUT_DIM 6325   // F*(3*NB-1)
#define OUT_PAD 6400
#define B_ROWS 4096
#define NBINS 8
#define TB_C 3.0f
#define MINB_C 0.001f
#define MIND_C 0.001f
#define DCONST_C 0.53974233f
#define LUEPS_C 0.001f
#define RSQRT_HID 0.08838834764831845f
#define CHUNK_ROWS 1024

typedef unsigned short ushort_t;
typedef __attribute__((ext_vector_type(8))) short short8;
typedef __attribute__((ext_vector_type(8))) unsigned short ushort8;
typedef __attribute__((ext_vector_type(4))) float f32x4;

__device__ __forceinline__ ushort_t f2bf(float f){
    union{float f; unsigned u;} v; v.f = f;
    unsigned r = v.u + 0x7fffu + ((v.u>>16)&1u);
    return (ushort_t)(r>>16);
}
__device__ __forceinline__ float bf2f(ushort_t h){
    union{unsigned u; float f;} v; v.u = ((unsigned)h)<<16;
    return v.f;
}
__device__ __forceinline__ float softplusf(float x){
    return fmaxf(x, 0.f) + log1pf(__expf(-fabsf(x)));
}

__device__ __forceinline__ void knots_from_u(const float* u, float* c, float* w){
    float m = u[0];
#pragma unroll
    for(int k=1;k<NBINS;k++) m = fmaxf(m, u[k]);
    float e[NBINS]; float s = 0.f;
#pragma unroll
    for(int k=0;k<NBINS;k++){ e[k] = __expf(u[k]-m); s += e[k]; }
    float inv = 1.f/s;
    float cum = 0.f;
    c[0] = -TB_C;
#pragma unroll
    for(int k=0;k<NBINS;k++){
        float v = MINB_C + (1.f - MINB_C*(float)NBINS)*e[k]*inv;
        cum += v;
        c[k+1] = 2.f*TB_C*cum - TB_C;
    }
    c[NBINS] = TB_C;
#pragma unroll
    for(int k=0;k<NBINS;k++) w[k] = c[k+1]-c[k];
}

__device__ __forceinline__ void rqs_inv(float x,
                                        const float* cw, const float* w,
                                        const float* ch, const float* h,
                                        const float* d,
                                        float& out, float& ld){
    bool inside = (x >= -TB_C) && (x <= TB_C);
    float xi = fminf(fmaxf(x, -TB_C), TB_C);
    int idx = 0;
#pragma unroll
    for(int j=1;j<NBINS;j++) idx += (xi >= ch[j]) ? 1 : 0;
    float icw=cw[0], iw=w[0], ich=ch[0], ih=h[0], d0=d[0], d1=d[1];
#pragma unroll
    for(int j=1;j<NBINS;j++){
        if(idx==j){ icw=cw[j]; iw=w[j]; ich=ch[j]; ih=h[j]; d0=d[j]; d1=d[j+1]; }
    }
    float delta = ih/iw;
    float t  = xi - ich;
    float s  = d0 + d1 - 2.f*delta;
    float a  = t*s + ih*(delta - d0);
    float b  = ih*d0 - t*s;
    float c  = -delta*t;
    float disc = b*b - 4.f*a*c;
    float root = 2.f*c / (-b - sqrtf(fmaxf(disc, 0.f)));
    float o  = root*iw + icw;
    float tm = root*(1.f-root);
    float den  = delta + s*tm;
    float dnum = delta*delta*(d1*root*root + 2.f*delta*tm + d0*(1.f-root)*(1.f-root));
    float l = 2.f*__logf(den) - __logf(dnum);
    out = inside ? o : x;
    ld  = inside ? l : 0.f;
}

// --------------------------- setup kernels ---------------------------------

__global__ void build_knots_kernel(const float* __restrict__ uw_u,
                                   const float* __restrict__ uh_u,
                                   const float* __restrict__ ud_u,
                                   float* __restrict__ knots){
    int g = blockIdx.x*blockDim.x + threadIdx.x;
    if(g >= 3*F_DIM) return;
    float* kb = knots + (size_t)g*43;
    float c[9], w[8];
    knots_from_u(uw_u + (size_t)g*8, c, w);
#pragma unroll
    for(int k=0;k<9;k++) kb[k]=c[k];
#pragma unroll
    for(int k=0;k<8;k++) kb[9+k]=w[k];
    knots_from_u(uh_u + (size_t)g*8, c, w);
#pragma unroll
    for(int k=0;k<9;k++) kb[17+k]=c[k];
#pragma unroll
    for(int k=0;k<8;k++) kb[26+k]=w[k];
    float dend = MIND_C + softplusf(DCONST_C);
    kb[34]=dend; kb[42]=dend;
    const float* ud = ud_u + (size_t)g*7;
#pragma unroll
    for(int k=0;k<7;k++) kb[35+k] = MIND_C + softplusf(ud[k]);
}

__global__ void logdiag_kernel(const float* __restrict__ lu_ud, float* __restrict__ outv){
    int tid = threadIdx.x;
    float s = 0.f;
    for(int k=tid; k<3*D_DIM; k+=256) s += __logf(softplusf(lu_ud[k]) + LUEPS_C);
#pragma unroll
    for(int o=32;o>0;o>>=1) s += __shfl_down(s, o);
    __shared__ float sm[4];
    if((tid&63)==0) sm[tid>>6]=s;
    __syncthreads();
    if(tid==0) outv[0] = sm[0]+sm[1]+sm[2]+sm[3];
}

// bf16 padded dense L [640][576] and transposed perm-scattered U^T:
//   Lmb[j][k]        = j>k ? lower[j][k] : (j==k ? 1 : 0)
//   UpTb[perm[k]][j] = j<k ? upper[j][k] : (j==k ? softplus(ud[k])+eps : 0)
// Buffers pre-zeroed (pad rows/cols). Then Apb = Lmb @ UpTb^T via MFMA gemm
// yields A with columns already scattered by perm, directly in Bt layout.
__global__ void build_LU_bf16(const float* __restrict__ lower,
                              const float* __restrict__ upper,
                              const float* __restrict__ ud,
                              const int* __restrict__ perm,
                              ushort_t* __restrict__ Lmb,
                              ushort_t* __restrict__ UpTb){
    int k = blockIdx.x*blockDim.x + threadIdx.x;
    int j = blockIdx.y;
    if(k >= D_DIM) return;
    float lv = (j>k) ? lower[(size_t)j*D_DIM+k] : (j==k ? 1.f : 0.f);
    Lmb[(size_t)j*D_PAD+k] = f2bf(lv);
    float uv;
    if(j<k)       uv = upper[(size_t)j*D_DIM+k];
    else if(j==k) uv = softplusf(ud[k]) + LUEPS_C;
    else          uv = 0.f;
    UpTb[(size_t)perm[k]*D_PAD + j] = f2bf(uv);
}

// fp32 [M][K] -> bf16 [Mpad][Kpad], zero-padded
__global__ void convert_pad(const float* __restrict__ in, ushort_t* __restrict__ out,
                            int M, int K, int Mpad, int Kpad){
    int idx = blockIdx.x*256 + threadIdx.x;
    if(idx >= Mpad*Kpad) return;
    int r = idx / Kpad, c = idx - r*Kpad;
    float v = (r<M && c<K) ? in[(size_t)r*K+c] : 0.f;
    out[idx] = f2bf(v);
}

// fp32 in[K][N] -> bf16 out[Npad][Kpad] (transpose), zero-padded. block 32x8.
__global__ void transpose_convert(const float* __restrict__ in, ushort_t* __restrict__ out,
                                  int K, int N, int Kpad, int Npad){
    __shared__ float t[32][33];
    int kb = blockIdx.x*32, nb = blockIdx.y*32;
    int tx = threadIdx.x, ty = threadIdx.y;
#pragma unroll
    for(int i=0;i<32;i+=8){
        int k = kb+ty+i, n = nb+tx;
        t[ty+i][tx] = (k<K && n<N) ? in[(size_t)k*N+n] : 0.f;
    }
    __syncthreads();
#pragma unroll
    for(int i=0;i<32;i+=8){
        int n = nb+ty+i, k = kb+tx;
        if(n<Npad && k<Kpad) out[(size_t)n*Kpad+k] = f2bf(t[tx][ty+i]);
    }
}

// zero the pad columns [550..576) of the two bf16 z buffers
__global__ void zero_pad_cols(ushort_t* __restrict__ z0, ushort_t* __restrict__ z1){
    int idx = blockIdx.x*256 + threadIdx.x;
    if(idx >= B_ROWS*(D_PAD-D_DIM)) return;
    int r = idx/(D_PAD-D_DIM), c = D_DIM + idx%(D_PAD-D_DIM);
    z0[(size_t)r*D_PAD+c]=0; z1[(size_t)r*D_PAD+c]=0;
}

// ------------------------------ bf16 MFMA gemm -----------------------------
// A: bf16 [M][Kpad] (rows up to grid.y*128 allocated)
// Bt: bf16 [Npad][Kpad], Npad >= gridDim.x*128
// C: [M][ldc=N] fp32 (OUTBF=0) or bf16 (OUTBF=1); bias fp32 [N]; Rm bf16 [M][N]
template<int RELU, int RESID, int OUTBF>
__global__ __launch_bounds__(256)
void gemm_mfma(const ushort_t* __restrict__ A, const ushort_t* __restrict__ Bt,
               const float* __restrict__ bias, const ushort_t* __restrict__ Rm,
               void* __restrict__ Cv, int M, int N, int Kpad){
    __shared__ ushort_t As[128][72];
    __shared__ ushort_t Bs[128][72];
    int tid = threadIdx.x;
    int row0 = blockIdx.y*128, col0 = blockIdx.x*128;
    int wave = tid>>6, lane = tid&63;
    int wm = wave&1, wn = wave>>1;
    int lm = lane&15, quad = lane>>4;
    f32x4 acc[4][4] = {};
    for(int k0=0; k0<Kpad; k0+=64){
#pragma unroll
        for(int it=0; it<4; it++){
            int c = tid + it*256;
            int r = c>>3, c8 = (c&7)*8;
            ushort8 va = *(const ushort8*)(A + (size_t)(row0+r)*Kpad + k0 + c8);
            if(RELU){
#pragma unroll
                for(int e=0;e<8;e++) va[e] = (va[e]&0x8000u) ? (unsigned short)0 : va[e];
            }
            *(ushort8*)&As[r][c8] = va;
            ushort8 vb = *(const ushort8*)(Bt + (size_t)(col0+r)*Kpad + k0 + c8);
            *(ushort8*)&Bs[r][c8] = vb;
        }
        __syncthreads();
#pragma unroll
        for(int ks=0; ks<2; ks++){
            short8 af[4], bfr[4];
#pragma unroll
            for(int i=0;i<4;i++){
                af[i]  = *(const short8*)&As[wm*64 + i*16 + lm][ks*32 + quad*8];
                bfr[i] = *(const short8*)&Bs[wn*64 + i*16 + lm][ks*32 + quad*8];
            }
#pragma unroll
            for(int i=0;i<4;i++)
#pragma unroll
                for(int j=0;j<4;j++)
                    acc[i][j] = __builtin_amdgcn_mfma_f32_16x16x32_bf16(af[i], bfr[j], acc[i][j], 0, 0, 0);
        }
        __syncthreads();
    }
#pragma unroll
    for(int i=0;i<4;i++){
        int rbase = row0 + wm*64 + i*16 + quad*4;
#pragma unroll
        for(int j=0;j<4;j++){
            int gc = col0 + wn*64 + j*16 + lm;
            if(gc >= N) continue;
            float bv = bias[gc];
#pragma unroll
            for(int r=0;r<4;r++){
                int gr = rbase + r;
                float v = acc[i][j][r] + bv;
                if(RESID) v += bf2f(Rm[(size_t)gr*N+gc]);
                if(OUTBF) ((ushort_t*)Cv)[(size_t)gr*N+gc] = f2bf(v);
                else      ((float*)Cv)[(size_t)gr*N+gc] = v;
            }
        }
    }
}

// --------------------------- spline kernels --------------------------------

__global__ __launch_bounds__(320)
void ident_spline_kernel(const float* __restrict__ z2, const float* __restrict__ knots,
                         int layer, ushort_t* __restrict__ identb,
                         float* __restrict__ znf, ushort_t* __restrict__ znb,
                         float* __restrict__ lq){
    int row = blockIdx.x; int tid = threadIdx.x;
    float ldv = 0.f;
    if(tid < F_DIM){
        const float* kb = knots + ((size_t)(layer*F_DIM + tid))*43;
        float x = z2[(size_t)row*D_DIM + 2*tid];
        float o, l;
        rqs_inv(x, kb, kb+9, kb+17, kb+26, kb+34, o, l);
        identb[(size_t)row*F_PAD + tid] = f2bf(o);
        znf[(size_t)row*D_DIM + 2*tid] = o;
        znb[(size_t)row*D_PAD + 2*tid] = f2bf(o);
        ldv = l;
    } else {
        identb[(size_t)row*F_PAD + tid] = 0;
    }
    __shared__ float sm[5];
    float v = ldv;
#pragma unroll
    for(int o=32;o>0;o>>=1) v += __shfl_down(v, o);
    if((tid&63)==0) sm[tid>>6]=v;
    __syncthreads();
    if(tid==0) lq[row] += sm[0]+sm[1]+sm[2]+sm[3]+sm[4];
}

__global__ __launch_bounds__(320)
void trans_spline_kernel(const ushort_t* __restrict__ p, const float* __restrict__ z2,
                         float* __restrict__ znf, ushort_t* __restrict__ znb,
                         float* __restrict__ lq, int row_base){
    __shared__ float pp[OUT_DIM];
    int lrow = blockIdx.x; int row = row_base + lrow;
    int tid = threadIdx.x;
    for(int k=tid; k<OUT_DIM; k+=320) pp[k] = bf2f(p[(size_t)lrow*OUT_DIM + k]);
    __syncthreads();
    float ldv = 0.f;
    if(tid < F_DIM){
        const float* q = &pp[tid*23];
        float uw[8], uh[8];
#pragma unroll
        for(int c=0;c<8;c++){ uw[c] = q[c]*RSQRT_HID; uh[c] = q[8+c]*RSQRT_HID; }
        float cw[9], w[8], ch[9], h[8], d[9];
        knots_from_u(uw, cw, w);
        knots_from_u(uh, ch, h);
        float dend = MIND_C + softplusf(DCONST_C);
        d[0]=dend; d[8]=dend;
#pragma unroll
        for(int c=0;c<7;c++) d[c+1] = MIND_C + softplusf(q[16+c]);
        float x = z2[(size_t)row*D_DIM + 2*tid + 1];
        float o, l;
        rqs_inv(x, cw, w, ch, h, d, o, l);
        znf[(size_t)row*D_DIM + 2*tid + 1] = o;
        znb[(size_t)row*D_PAD + 2*tid + 1] = f2bf(o);
        ldv = l;
    }
    __shared__ float sm[5];
    float v = ldv;
#pragma unroll
    for(int o=32;o>0;o>>=1) v += __shfl_down(v, o);
    if((tid&63)==0) sm[tid>>6]=v;
    __syncthreads();
    if(tid==0) lq[row] += sm[0]+sm[1]+sm[2]+sm[3]+sm[4];
}

__global__ __launch_bounds__(320)
void finalize_kernel(const float* __restrict__ z, const float* __restrict__ loc,
                     const float* __restrict__ lsc, const float* __restrict__ lq,
                     const float* __restrict__ logdiag, float* __restrict__ out){
    int row = blockIdx.x; int tid = threadIdx.x;
    float s = 0.f;
    for(int k=tid; k<D_DIM; k+=320){
        float l = lsc[k];
        float diff = (z[(size_t)row*D_DIM+k]-loc[k])*__expf(-l);
        s += l + 0.5f*diff*diff;
    }
    __shared__ float sm[5];
#pragma unroll
    for(int o=32;o>0;o>>=1) s += __shfl_down(s, o);
    if((tid&63)==0) sm[tid>>6]=s;
    __syncthreads();
    if(tid==0){
        float tot = sm[0]+sm[1]+sm[2]+sm[3]+sm[4];
        out[row] = lq[row] + logdiag[0] - 275.f*1.8378770664f - tot;
    }
}

// ---------------------------------------------------------------------------

extern "C" void kernel_launch(void* const* d_in, const int* in_sizes, int n_in,
                              void* d_out, int out_size, void* d_ws, size_t ws_size,
                              hipStream_t stream){
    const float* x        = (const float*)d_in[0];
    const float* loc      = (const float*)d_in[1];
    const float* lsc      = (const float*)d_in[2];
    const float* Wi       = (const float*)d_in[3];
    const float* bi       = (const float*)d_in[4];
    const float* Wb       = (const float*)d_in[5];
    const float* bb       = (const float*)d_in[6];
    const float* Wo       = (const float*)d_in[7];
    const float* bo       = (const float*)d_in[8];
    const float* uw_u     = (const float*)d_in[9];
    const float* uh_u     = (const float*)d_in[10];
    const float* ud_u     = (const float*)d_in[11];
    const float* lu_lower = (const float*)d_in[12];
    const float* lu_upper = (const float*)d_in[13];
    const float* lu_ud    = (const float*)d_in[14];
    const float* lu_b     = (const float*)d_in[15];
    const int*   perms    = (const int*)d_in[16];
    float* out = (float*)d_out;

    char* base = (char*)d_ws;
    size_t off = 0;
    auto alloc = [&](size_t bytes)->char*{
        char* p = base + off;
        off += (bytes + 255) & ~(size_t)255;
        return p;
    };
    float* lq      = (float*)alloc(B_ROWS*4);
    float* zbias   = (float*)alloc(D_PAD*4);
    float* logdiag = (float*)alloc(64*4);
    float* knots   = (float*)alloc((size_t)3*F_DIM*43*4);
    float* z2      = (float*)alloc((size_t)B_ROWS*D_DIM*4);
    float* zf0     = (float*)alloc((size_t)B_ROWS*D_DIM*4);
    float* zf1     = (float*)alloc((size_t)B_ROWS*D_DIM*4);
    ushort_t* pbuf = (ushort_t*)alloc((size_t)CHUNK_ROWS*OUT_DIM*2);
    ushort_t* xb   = (ushort_t*)alloc((size_t)B_ROWS*D_PAD*2);
    ushort_t* zbf0 = (ushort_t*)alloc((size_t)B_ROWS*D_PAD*2);
    ushort_t* zbf1 = (ushort_t*)alloc((size_t)B_ROWS*D_PAD*2);
    ushort_t* Lmb  = (ushort_t*)alloc((size_t)N_PAD_A*D_PAD*2);
    ushort_t* UpTb = (ushort_t*)alloc((size_t)N_PAD_A*D_PAD*2);
    ushort_t* Apb  = (ushort_t*)alloc((size_t)N_PAD_A*D_PAD*2);
    ushort_t* identb=(ushort_t*)alloc((size_t)B_ROWS*F_PAD*2);
    ushort_t* tb   = (ushort_t*)alloc((size_t)B_ROWS*HID_DIM*2);
    ushort_t* rb   = (ushort_t*)alloc((size_t)B_ROWS*HID_DIM*2);
    ushort_t* WiT  = (ushort_t*)alloc((size_t)HID_DIM*F_PAD*2);
    ushort_t* WbT  = (ushort_t*)alloc((size_t)4*HID_DIM*HID_DIM*2);
    ushort_t* WoT  = (ushort_t*)alloc((size_t)OUT_PAD*HID_DIM*2);

    hipMemsetAsync(lq, 0, B_ROWS*sizeof(float), stream);
    hipMemsetAsync(zbias, 0, D_PAD*sizeof(float), stream);
    build_knots_kernel<<<dim3((3*F_DIM+255)/256), dim3(256), 0, stream>>>(uw_u, uh_u, ud_u, knots);
    logdiag_kernel<<<dim3(1), dim3(256), 0, stream>>>(lu_ud, logdiag);
    zero_pad_cols<<<dim3((B_ROWS*(D_PAD-D_DIM)+255)/256), dim3(256), 0, stream>>>(zbf0, zbf1);
    convert_pad<<<dim3((B_ROWS*D_PAD+255)/256), dim3(256), 0, stream>>>(
        x, xb, B_ROWS, D_DIM, B_ROWS, D_PAD);

    const ushort_t* zcur_b = xb;
    const float* zcur_f = nullptr;
    ushort_t* zbf[2] = {zbf0, zbf1};
    float* zf[2] = {zf0, zf1};
    int zi = 0;
    dim3 tthr(32,8);

    for(int it=0; it<3; ++it){
        int i = 2 - it;
        const float* Wbl = Wb + (size_t)i*4*HID_DIM*HID_DIM;
        const float* bbl = bb + (size_t)i*4*HID_DIM;

        // ---- A = L@U (perm folded into U^T rows), all-bf16 MFMA
        hipMemsetAsync(Lmb, 0, (size_t)N_PAD_A*D_PAD*2, stream);
        hipMemsetAsync(UpTb, 0, (size_t)N_PAD_A*D_PAD*2, stream);
        build_LU_bf16<<<dim3((D_DIM+255)/256, D_DIM), dim3(256), 0, stream>>>(
            lu_lower + (size_t)i*D_DIM*D_DIM, lu_upper + (size_t)i*D_DIM*D_DIM,
            lu_ud + (size_t)i*D_DIM, perms + (size_t)i*D_DIM, Lmb, UpTb);
        gemm_mfma<0,0,1><<<dim3(5, 5), dim3(256), 0, stream>>>(
            Lmb, UpTb, zbias, nullptr, Apb, N_PAD_A, D_PAD, D_PAD);

        // ---- weight transposes (bf16 [n][k])
        transpose_convert<<<dim3(F_PAD/32, HID_DIM/32), tthr, 0, stream>>>(
            Wi + (size_t)i*F_DIM*HID_DIM, WiT, F_DIM, HID_DIM, F_PAD, HID_DIM);
        for(int j=0;j<4;j++)
            transpose_convert<<<dim3(HID_DIM/32, HID_DIM/32), tthr, 0, stream>>>(
                Wbl + (size_t)j*HID_DIM*HID_DIM, WbT + (size_t)j*HID_DIM*HID_DIM,
                HID_DIM, HID_DIM, HID_DIM, HID_DIM);
        transpose_convert<<<dim3(HID_DIM/32, OUT_PAD/32), tthr, 0, stream>>>(
            Wo + (size_t)i*HID_DIM*OUT_DIM, WoT, HID_DIM, OUT_DIM, HID_DIM, OUT_PAD);

        // ---- z2 = z @ Ap^T + lu_b  (MFMA)
        gemm_mfma<0,0,0><<<dim3(N_PAD_A/128, B_ROWS/128), dim3(256), 0, stream>>>(
            zcur_b, Apb, lu_b + (size_t)i*D_DIM, nullptr, z2, B_ROWS, D_DIM, D_PAD);

        ident_spline_kernel<<<dim3(B_ROWS), dim3(320), 0, stream>>>(
            z2, knots, i, identb, zf[zi], zbf[zi], lq);

        // ---- resnet (MFMA, bf16 intermediates)
        gemm_mfma<0,0,1><<<dim3(1, B_ROWS/128), dim3(256), 0, stream>>>(
            identb, WiT, bi + (size_t)i*HID_DIM, nullptr, tb, B_ROWS, HID_DIM, F_PAD);
        gemm_mfma<1,0,1><<<dim3(1, B_ROWS/128), dim3(256), 0, stream>>>(
            tb, WbT + 0*HID_DIM*HID_DIM, bbl + 0*HID_DIM, nullptr, rb, B_ROWS, HID_DIM, HID_DIM);
        gemm_mfma<1,1,1><<<dim3(1, B_ROWS/128), dim3(256), 0, stream>>>(
            rb, WbT + 1*HID_DIM*HID_DIM, bbl + 1*HID_DIM, tb, tb, B_ROWS, HID_DIM, HID_DIM);
        gemm_mfma<1,0,1><<<dim3(1, B_ROWS/128), dim3(256), 0, stream>>>(
            tb, WbT + 2*HID_DIM*HID_DIM, bbl + 2*HID_DIM, nullptr, rb, B_ROWS, HID_DIM, HID_DIM);
        gemm_mfma<1,1,1><<<dim3(1, B_ROWS/128), dim3(256), 0, stream>>>(
            rb, WbT + 3*HID_DIM*HID_DIM, bbl + 3*HID_DIM, tb, tb, B_ROWS, HID_DIM, HID_DIM);

        // ---- p (chunked, bf16) + conditional spline
        for(int c=0; c<B_ROWS/CHUNK_ROWS; ++c){
            gemm_mfma<0,0,1><<<dim3(OUT_PAD/128, CHUNK_ROWS/128), dim3(256), 0, stream>>>(
                tb + (size_t)c*CHUNK_ROWS*HID_DIM, WoT, bo + (size_t)i*OUT_DIM, nullptr,
                pbuf, CHUNK_ROWS, OUT_DIM, HID_DIM);
            trans_spline_kernel<<<dim3(CHUNK_ROWS), dim3(320), 0, stream>>>(
                pbuf, z2, zf[zi], zbf[zi], lq, c*CHUNK_ROWS);
        }

        zcur_b = zbf[zi];
        zcur_f = zf[zi];
        zi ^= 1;
    }

    finalize_kernel<<<dim3(B_ROWS), dim3(320), 0, stream>>>(
        zcur_f, loc, lsc, lq, logdiag, out);
}

// Round 6
// 572.080 us; speedup vs baseline: 3.7399x; 1.5021x over previous
//
#include <hip/hip_runtime.h>

// ---------------------------------------------------------------------------
// DensityEstimator: 3-layer neural spline flow inverse log-prob.
// R5: fix resnet_fused Ws staging indexing (v>>3 -> v>>4 for 128-col rows;
//     was OOB LDS write -> NaN). Otherwise identical to R4:
//     (1) Wo columns group-reordered (param-major), coalesced trans_spline,
//         single full-batch Wo gemm; (2) fused resnet (5 gemms -> 1);
//     (3) layer-batched setup.
// ---------------------------------------------------------------------------

#define D_DIM 550
#define D_PAD 576
#define N_PAD_A 640
#define F_DIM 275
#define F_PAD 320
#define HID_DIM 128
#define OUT_DIM 6325
#define OUT_PAD 6400
#define B_ROWS 4096
#define NBINS 8
#define TB_C 3.0f
#define MINB_C 0.001f
#define MIND_C 0.001f
#define DCONST_C 0.53974233f
#define LUEPS_C 0.001f
#define RSQRT_HID 0.08838834764831845f

typedef unsigned short ushort_t;
typedef __attribute__((ext_vector_type(8))) short short8;
typedef __attribute__((ext_vector_type(8))) unsigned short ushort8;
typedef __attribute__((ext_vector_type(4))) float f32x4;

__device__ __forceinline__ ushort_t f2bf(float f){
    union{float f; unsigned u;} v; v.f = f;
    unsigned r = v.u + 0x7fffu + ((v.u>>16)&1u);
    return (ushort_t)(r>>16);
}
__device__ __forceinline__ float bf2f(ushort_t h){
    union{unsigned u; float f;} v; v.u = ((unsigned)h)<<16;
    return v.f;
}
__device__ __forceinline__ float softplusf(float x){
    return fmaxf(x, 0.f) + log1pf(__expf(-fabsf(x)));
}

__device__ __forceinline__ void knots_from_u(const float* u, float* c, float* w){
    float m = u[0];
#pragma unroll
    for(int k=1;k<NBINS;k++) m = fmaxf(m, u[k]);
    float e[NBINS]; float s = 0.f;
#pragma unroll
    for(int k=0;k<NBINS;k++){ e[k] = __expf(u[k]-m); s += e[k]; }
    float inv = 1.f/s;
    float cum = 0.f;
    c[0] = -TB_C;
#pragma unroll
    for(int k=0;k<NBINS;k++){
        float v = MINB_C + (1.f - MINB_C*(float)NBINS)*e[k]*inv;
        cum += v;
        c[k+1] = 2.f*TB_C*cum - TB_C;
    }
    c[NBINS] = TB_C;
#pragma unroll
    for(int k=0;k<NBINS;k++) w[k] = c[k+1]-c[k];
}

__device__ __forceinline__ void rqs_inv(float x,
                                        const float* cw, const float* w,
                                        const float* ch, const float* h,
                                        const float* d,
                                        float& out, float& ld){
    bool inside = (x >= -TB_C) && (x <= TB_C);
    float xi = fminf(fmaxf(x, -TB_C), TB_C);
    int idx = 0;
#pragma unroll
    for(int j=1;j<NBINS;j++) idx += (xi >= ch[j]) ? 1 : 0;
    float icw=cw[0], iw=w[0], ich=ch[0], ih=h[0], d0=d[0], d1=d[1];
#pragma unroll
    for(int j=1;j<NBINS;j++){
        if(idx==j){ icw=cw[j]; iw=w[j]; ich=ch[j]; ih=h[j]; d0=d[j]; d1=d[j+1]; }
    }
    float delta = ih/iw;
    float t  = xi - ich;
    float s  = d0 + d1 - 2.f*delta;
    float a  = t*s + ih*(delta - d0);
    float b  = ih*d0 - t*s;
    float c  = -delta*t;
    float disc = b*b - 4.f*a*c;
    float root = 2.f*c / (-b - sqrtf(fmaxf(disc, 0.f)));
    float o  = root*iw + icw;
    float tm = root*(1.f-root);
    float den  = delta + s*tm;
    float dnum = delta*delta*(d1*root*root + 2.f*delta*tm + d0*(1.f-root)*(1.f-root));
    float l = 2.f*__logf(den) - __logf(dnum);
    out = inside ? o : x;
    ld  = inside ? l : 0.f;
}

// --------------------------- setup kernels ---------------------------------

__global__ void build_knots_kernel(const float* __restrict__ uw_u,
                                   const float* __restrict__ uh_u,
                                   const float* __restrict__ ud_u,
                                   float* __restrict__ knots){
    int g = blockIdx.x*blockDim.x + threadIdx.x;
    if(g >= 3*F_DIM) return;
    float* kb = knots + (size_t)g*43;
    float c[9], w[8];
    knots_from_u(uw_u + (size_t)g*8, c, w);
#pragma unroll
    for(int k=0;k<9;k++) kb[k]=c[k];
#pragma unroll
    for(int k=0;k<8;k++) kb[9+k]=w[k];
    knots_from_u(uh_u + (size_t)g*8, c, w);
#pragma unroll
    for(int k=0;k<9;k++) kb[17+k]=c[k];
#pragma unroll
    for(int k=0;k<8;k++) kb[26+k]=w[k];
    float dend = MIND_C + softplusf(DCONST_C);
    kb[34]=dend; kb[42]=dend;
    const float* ud = ud_u + (size_t)g*7;
#pragma unroll
    for(int k=0;k<7;k++) kb[35+k] = MIND_C + softplusf(ud[k]);
}

__global__ void logdiag_kernel(const float* __restrict__ lu_ud, float* __restrict__ outv){
    int tid = threadIdx.x;
    float s = 0.f;
    for(int k=tid; k<3*D_DIM; k+=256) s += __logf(softplusf(lu_ud[k]) + LUEPS_C);
#pragma unroll
    for(int o=32;o>0;o>>=1) s += __shfl_down(s, o);
    __shared__ float sm[4];
    if((tid&63)==0) sm[tid>>6]=s;
    __syncthreads();
    if(tid==0) outv[0] = sm[0]+sm[1]+sm[2]+sm[3];
}

// batched over layers (blockIdx.z)
__global__ void build_LU_bf16(const float* __restrict__ lower,
                              const float* __restrict__ upper,
                              const float* __restrict__ ud,
                              const int* __restrict__ perm,
                              ushort_t* __restrict__ Lmb,
                              ushort_t* __restrict__ UpTb){
    int l = blockIdx.z;
    lower += (size_t)l*D_DIM*D_DIM; upper += (size_t)l*D_DIM*D_DIM;
    ud += (size_t)l*D_DIM; perm += (size_t)l*D_DIM;
    Lmb += (size_t)l*N_PAD_A*D_PAD; UpTb += (size_t)l*N_PAD_A*D_PAD;
    int k = blockIdx.x*blockDim.x + threadIdx.x;
    int j = blockIdx.y;
    if(k >= D_DIM) return;
    float lv = (j>k) ? lower[(size_t)j*D_DIM+k] : (j==k ? 1.f : 0.f);
    Lmb[(size_t)j*D_PAD+k] = f2bf(lv);
    float uv;
    if(j<k)       uv = upper[(size_t)j*D_DIM+k];
    else if(j==k) uv = softplusf(ud[k]) + LUEPS_C;
    else          uv = 0.f;
    UpTb[(size_t)perm[k]*D_PAD + j] = f2bf(uv);
}

__global__ void convert_pad(const float* __restrict__ in, ushort_t* __restrict__ out,
                            int M, int K, int Mpad, int Kpad){
    int idx = blockIdx.x*256 + threadIdx.x;
    if(idx >= Mpad*Kpad) return;
    int r = idx / Kpad, c = idx - r*Kpad;
    float v = (r<M && c<K) ? in[(size_t)r*K+c] : 0.f;
    out[idx] = f2bf(v);
}

// fp32 in[K][N] -> bf16 out[Npad][Kpad], batched over blockIdx.z with strides.
// REMAP=1: dest row ng = (n%23)*275 + n/23 for n<6325 (param-major grouping).
template<int REMAP>
__global__ void transpose_convert(const float* __restrict__ in, ushort_t* __restrict__ out,
                                  int K, int N, int Kpad, int Npad, long s_in, long s_out){
    in += (size_t)blockIdx.z*s_in; out += (size_t)blockIdx.z*s_out;
    __shared__ float t[32][33];
    int kb = blockIdx.x*32, nb = blockIdx.y*32;
    int tx = threadIdx.x, ty = threadIdx.y;
#pragma unroll
    for(int i=0;i<32;i+=8){
        int k = kb+ty+i, n = nb+tx;
        t[ty+i][tx] = (k<K && n<N) ? in[(size_t)k*N+n] : 0.f;
    }
    __syncthreads();
#pragma unroll
    for(int i=0;i<32;i+=8){
        int n = nb+ty+i, k = kb+tx;
        if(n<Npad && k<Kpad){
            int ng = n;
            if(REMAP && n < OUT_DIM) ng = (n%23)*F_DIM + n/23;
            out[(size_t)ng*Kpad+k] = f2bf(t[tx][ty+i]);
        }
    }
}

// bo -> grouped layout, all 3 layers
__global__ void reorder_bias(const float* __restrict__ bo, float* __restrict__ bo_g){
    int idx = blockIdx.x*256 + threadIdx.x;
    if(idx >= 3*OUT_PAD) return;
    int l = idx/OUT_PAD, ng = idx%OUT_PAD;
    float v = 0.f;
    if(ng < OUT_DIM){ int f = ng%F_DIM, j = ng/F_DIM; v = bo[(size_t)l*OUT_DIM + f*23 + j]; }
    bo_g[idx] = v;
}

__global__ void zero_pad_cols(ushort_t* __restrict__ z0, ushort_t* __restrict__ z1){
    int idx = blockIdx.x*256 + threadIdx.x;
    if(idx >= B_ROWS*(D_PAD-D_DIM)) return;
    int r = idx/(D_PAD-D_DIM), c = D_DIM + idx%(D_PAD-D_DIM);
    z0[(size_t)r*D_PAD+c]=0; z1[(size_t)r*D_PAD+c]=0;
}

// ------------------------------ bf16 MFMA gemm -----------------------------
// A [M][Kpad] bf16, Bt [Npad][Kpad] bf16, C [M][ldc=N], bias fp32 [N].
// Batched via blockIdx.z with element strides sA,sB,sC (bias shared).
template<int OUTBF>
__global__ __launch_bounds__(256)
void gemm_mfma(const ushort_t* __restrict__ A, const ushort_t* __restrict__ Bt,
               const float* __restrict__ bias, void* __restrict__ Cv,
               int M, int N, int Kpad, long sA, long sB, long sC){
    A  += (size_t)blockIdx.z*sA;
    Bt += (size_t)blockIdx.z*sB;
    __shared__ ushort_t As[128][72];
    __shared__ ushort_t Bs[128][72];
    int tid = threadIdx.x;
    int row0 = blockIdx.y*128, col0 = blockIdx.x*128;
    int wave = tid>>6, lane = tid&63;
    int wm = wave&1, wn = wave>>1;
    int lm = lane&15, quad = lane>>4;
    f32x4 acc[4][4] = {};
    for(int k0=0; k0<Kpad; k0+=64){
#pragma unroll
        for(int it=0; it<4; it++){
            int c = tid + it*256;
            int r = c>>3, c8 = (c&7)*8;
            *(ushort8*)&As[r][c8] = *(const ushort8*)(A + (size_t)(row0+r)*Kpad + k0 + c8);
            *(ushort8*)&Bs[r][c8] = *(const ushort8*)(Bt + (size_t)(col0+r)*Kpad + k0 + c8);
        }
        __syncthreads();
#pragma unroll
        for(int ks=0; ks<2; ks++){
            short8 af[4], bfr[4];
#pragma unroll
            for(int i=0;i<4;i++){
                af[i]  = *(const short8*)&As[wm*64 + i*16 + lm][ks*32 + quad*8];
                bfr[i] = *(const short8*)&Bs[wn*64 + i*16 + lm][ks*32 + quad*8];
            }
#pragma unroll
            for(int i=0;i<4;i++)
#pragma unroll
                for(int j=0;j<4;j++)
                    acc[i][j] = __builtin_amdgcn_mfma_f32_16x16x32_bf16(af[i], bfr[j], acc[i][j], 0, 0, 0);
        }
        __syncthreads();
    }
#pragma unroll
    for(int i=0;i<4;i++){
        int rbase = row0 + wm*64 + i*16 + quad*4;
#pragma unroll
        for(int j=0;j<4;j++){
            int gc = col0 + wn*64 + j*16 + lm;
            if(gc >= N) continue;
            float bv = bias[gc];
#pragma unroll
            for(int r=0;r<4;r++){
                int gr = rbase + r;
                float v = acc[i][j][r] + bv;
                if(OUTBF) ((ushort_t*)Cv + (size_t)blockIdx.z*sC)[(size_t)gr*N+gc] = f2bf(v);
                else      ((float*)Cv + (size_t)blockIdx.z*sC)[(size_t)gr*N+gc] = v;
            }
        }
    }
}

// ------------------------------ fused resnet -------------------------------
// One block per 64 rows; all 5 gemm stages in-kernel, weights LDS-staged.
__global__ __launch_bounds__(256)
void resnet_fused(const ushort_t* __restrict__ identb,  // [B][F_PAD]
                  const ushort_t* __restrict__ WiT,     // [128][F_PAD]
                  const float* __restrict__ bi,         // [128]
                  const ushort_t* __restrict__ WbT,     // [4][128][128]
                  const float* __restrict__ bb,         // [4][128]
                  ushort_t* __restrict__ tb){           // [B][128]
    __shared__ __align__(16) char smem[(64*136 + 128*136)*2];
    ushort_t (*As2)[136] = (ushort_t(*)[136])smem;               // 64 rows (stages 2-5 A)
    ushort_t (*Ws)[136]  = (ushort_t(*)[136])(smem + 64*136*2);  // 128 rows (stages 2-5 W)
    ushort_t (*As1)[72]  = (ushort_t(*)[72])smem;                // stage-1 A tile
    ushort_t (*Bs1)[72]  = (ushort_t(*)[72])(smem + 64*136*2);   // stage-1 W tile
    int tid = threadIdx.x, wave = tid>>6, lane = tid&63;
    int lm = lane&15, quad = lane>>4;
    int r0 = blockIdx.x*64;
    f32x4 cur[8] = {};
    f32x4 tsv[8];
    // ---- stage 1: t = ident @ Wi  (K = 320)
    for(int k0=0; k0<F_PAD; k0+=64){
#pragma unroll
        for(int it=0; it<2; it++){
            int v = tid + it*256; int r = v>>3, c8 = (v&7)*8;   // 64-col rows: 8 slots/row
            *(ushort8*)&As1[r][c8] = *(const ushort8*)(identb + (size_t)(r0+r)*F_PAD + k0 + c8);
        }
#pragma unroll
        for(int it=0; it<4; it++){
            int v = tid + it*256; int n = v>>3, c8 = (v&7)*8;   // 64-col rows
            *(ushort8*)&Bs1[n][c8] = *(const ushort8*)(WiT + (size_t)n*F_PAD + k0 + c8);
        }
        __syncthreads();
#pragma unroll
        for(int ks=0; ks<2; ks++){
            short8 af = *(const short8*)&As1[wave*16 + lm][ks*32 + quad*8];
#pragma unroll
            for(int j=0;j<8;j++){
                short8 bf = *(const short8*)&Bs1[j*16 + lm][ks*32 + quad*8];
                cur[j] = __builtin_amdgcn_mfma_f32_16x16x32_bf16(af, bf, cur[j], 0, 0, 0);
            }
        }
        __syncthreads();
    }
#pragma unroll
    for(int j=0;j<8;j++){
        float bv = bi[j*16 + lm];
#pragma unroll
        for(int r=0;r<4;r++) cur[j][r] += bv;
        tsv[j] = cur[j];
    }
    // ---- stages 2-5 (K = 128 each)
    for(int st=0; st<4; st++){
#pragma unroll
        for(int j=0;j<8;j++)
#pragma unroll
            for(int r=0;r<4;r++)
                As2[wave*16 + quad*4 + r][j*16 + lm] = f2bf(fmaxf(cur[j][r], 0.f));
#pragma unroll
        for(int it=0; it<8; it++){
            int v = tid + it*256; int n = v>>4, c8 = (v&15)*8;  // 128-col rows: 16 slots/row (R5 fix)
            *(ushort8*)&Ws[n][c8] = *(const ushort8*)(WbT + (size_t)st*128*128 + (size_t)n*128 + c8);
        }
        __syncthreads();
        f32x4 acc[8] = {};
#pragma unroll
        for(int ks=0; ks<4; ks++){
            short8 af = *(const short8*)&As2[wave*16 + lm][ks*32 + quad*8];
#pragma unroll
            for(int j=0;j<8;j++){
                short8 bf = *(const short8*)&Ws[j*16 + lm][ks*32 + quad*8];
                acc[j] = __builtin_amdgcn_mfma_f32_16x16x32_bf16(af, bf, acc[j], 0, 0, 0);
            }
        }
        __syncthreads();
#pragma unroll
        for(int j=0;j<8;j++){
            float bv = bb[st*128 + j*16 + lm];
#pragma unroll
            for(int r=0;r<4;r++) acc[j][r] += bv;
        }
        if(st==1 || st==3){
#pragma unroll
            for(int j=0;j<8;j++){
#pragma unroll
                for(int r=0;r<4;r++) acc[j][r] += tsv[j][r];
                tsv[j] = acc[j];
            }
        }
#pragma unroll
        for(int j=0;j<8;j++) cur[j] = acc[j];
    }
#pragma unroll
    for(int j=0;j<8;j++)
#pragma unroll
        for(int r=0;r<4;r++)
            tb[(size_t)(r0 + wave*16 + quad*4 + r)*HID_DIM + j*16 + lm] = f2bf(cur[j][r]);
}

// --------------------------- spline kernels --------------------------------

__global__ __launch_bounds__(320)
void ident_spline_kernel(const float* __restrict__ z2, const float* __restrict__ knots,
                         int layer, ushort_t* __restrict__ identb,
                         float* __restrict__ znf, ushort_t* __restrict__ znb,
                         float* __restrict__ lq){
    int row = blockIdx.x; int tid = threadIdx.x;
    float ldv = 0.f;
    if(tid < F_DIM){
        const float* kb = knots + ((size_t)(layer*F_DIM + tid))*43;
        float x = z2[(size_t)row*D_DIM + 2*tid];
        float o, l;
        rqs_inv(x, kb, kb+9, kb+17, kb+26, kb+34, o, l);
        identb[(size_t)row*F_PAD + tid] = f2bf(o);
        znf[(size_t)row*D_DIM + 2*tid] = o;
        znb[(size_t)row*D_PAD + 2*tid] = f2bf(o);
        ldv = l;
    } else {
        identb[(size_t)row*F_PAD + tid] = 0;
    }
    __shared__ float sm[5];
    float v = ldv;
#pragma unroll
    for(int o=32;o>0;o>>=1) v += __shfl_down(v, o);
    if((tid&63)==0) sm[tid>>6]=v;
    __syncthreads();
    if(tid==0) lq[row] += sm[0]+sm[1]+sm[2]+sm[3]+sm[4];
}

// p in grouped layout pg[row][j*275+f], ldc OUT_PAD -> coalesced reads, no LDS.
__global__ __launch_bounds__(320)
void trans_spline_kernel(const ushort_t* __restrict__ pg, const float* __restrict__ z2,
                         float* __restrict__ znf, ushort_t* __restrict__ znb,
                         float* __restrict__ lq){
    int row = blockIdx.x; int tid = threadIdx.x;
    float ldv = 0.f;
    if(tid < F_DIM){
        const ushort_t* q = pg + (size_t)row*OUT_PAD + tid;
        float uw[8], uh[8];
#pragma unroll
        for(int c=0;c<8;c++){
            uw[c] = bf2f(q[(size_t)c*F_DIM])*RSQRT_HID;
            uh[c] = bf2f(q[(size_t)(8+c)*F_DIM])*RSQRT_HID;
        }
        float cw[9], w[8], ch[9], h[8], d[9];
        knots_from_u(uw, cw, w);
        knots_from_u(uh, ch, h);
        float dend = MIND_C + softplusf(DCONST_C);
        d[0]=dend; d[8]=dend;
#pragma unroll
        for(int c=0;c<7;c++) d[c+1] = MIND_C + softplusf(bf2f(q[(size_t)(16+c)*F_DIM]));
        float x = z2[(size_t)row*D_DIM + 2*tid + 1];
        float o, l;
        rqs_inv(x, cw, w, ch, h, d, o, l);
        znf[(size_t)row*D_DIM + 2*tid + 1] = o;
        znb[(size_t)row*D_PAD + 2*tid + 1] = f2bf(o);
        ldv = l;
    }
    __shared__ float sm[5];
    float v = ldv;
#pragma unroll
    for(int o=32;o>0;o>>=1) v += __shfl_down(v, o);
    if((tid&63)==0) sm[tid>>6]=v;
    __syncthreads();
    if(tid==0) lq[row] += sm[0]+sm[1]+sm[2]+sm[3]+sm[4];
}

__global__ __launch_bounds__(320)
void finalize_kernel(const float* __restrict__ z, const float* __restrict__ loc,
                     const float* __restrict__ lsc, const float* __restrict__ lq,
                     const float* __restrict__ logdiag, float* __restrict__ out){
    int row = blockIdx.x; int tid = threadIdx.x;
    float s = 0.f;
    for(int k=tid; k<D_DIM; k+=320){
        float l = lsc[k];
        float diff = (z[(size_t)row*D_DIM+k]-loc[k])*__expf(-l);
        s += l + 0.5f*diff*diff;
    }
    __shared__ float sm[5];
#pragma unroll
    for(int o=32;o>0;o>>=1) s += __shfl_down(s, o);
    if((tid&63)==0) sm[tid>>6]=s;
    __syncthreads();
    if(tid==0){
        float tot = sm[0]+sm[1]+sm[2]+sm[3]+sm[4];
        out[row] = lq[row] + logdiag[0] - 275.f*1.8378770664f - tot;
    }
}

// ---------------------------------------------------------------------------

extern "C" void kernel_launch(void* const* d_in, const int* in_sizes, int n_in,
                              void* d_out, int out_size, void* d_ws, size_t ws_size,
                              hipStream_t stream){
    const float* x        = (const float*)d_in[0];
    const float* loc      = (const float*)d_in[1];
    const float* lsc      = (const float*)d_in[2];
    const float* Wi       = (const float*)d_in[3];
    const float* bi       = (const float*)d_in[4];
    const float* Wb       = (const float*)d_in[5];
    const float* bb       = (const float*)d_in[6];
    const float* Wo       = (const float*)d_in[7];
    const float* bo       = (const float*)d_in[8];
    const float* uw_u     = (const float*)d_in[9];
    const float* uh_u     = (const float*)d_in[10];
    const float* ud_u     = (const float*)d_in[11];
    const float* lu_lower = (const float*)d_in[12];
    const float* lu_upper = (const float*)d_in[13];
    const float* lu_ud    = (const float*)d_in[14];
    const float* lu_b     = (const float*)d_in[15];
    const int*   perms    = (const int*)d_in[16];
    float* out = (float*)d_out;

    char* base = (char*)d_ws;
    size_t off = 0;
    auto alloc = [&](size_t bytes)->char*{
        char* p = base + off;
        off += (bytes + 255) & ~(size_t)255;
        return p;
    };
    float* lq      = (float*)alloc(B_ROWS*4);
    float* zbias   = (float*)alloc(D_PAD*4);
    float* logdiag = (float*)alloc(64*4);
    float* knots   = (float*)alloc((size_t)3*F_DIM*43*4);
    float* z2      = (float*)alloc((size_t)B_ROWS*D_DIM*4);
    float* zf0     = (float*)alloc((size_t)B_ROWS*D_DIM*4);
    float* zf1     = (float*)alloc((size_t)B_ROWS*D_DIM*4);
    float* bo_g    = (float*)alloc((size_t)3*OUT_PAD*4);
    ushort_t* pbuf = (ushort_t*)alloc((size_t)B_ROWS*OUT_PAD*2);
    ushort_t* xb   = (ushort_t*)alloc((size_t)B_ROWS*D_PAD*2);
    ushort_t* zbf0 = (ushort_t*)alloc((size_t)B_ROWS*D_PAD*2);
    ushort_t* zbf1 = (ushort_t*)alloc((size_t)B_ROWS*D_PAD*2);
    ushort_t* Lmb  = (ushort_t*)alloc((size_t)3*N_PAD_A*D_PAD*2);
    ushort_t* UpTb = (ushort_t*)alloc((size_t)3*N_PAD_A*D_PAD*2);
    ushort_t* Apb  = (ushort_t*)alloc((size_t)3*N_PAD_A*D_PAD*2);
    ushort_t* identb=(ushort_t*)alloc((size_t)B_ROWS*F_PAD*2);
    ushort_t* tb   = (ushort_t*)alloc((size_t)B_ROWS*HID_DIM*2);
    ushort_t* WiT  = (ushort_t*)alloc((size_t)3*HID_DIM*F_PAD*2);
    ushort_t* WbT  = (ushort_t*)alloc((size_t)3*4*HID_DIM*HID_DIM*2);
    ushort_t* WoT  = (ushort_t*)alloc((size_t)3*OUT_PAD*HID_DIM*2);

    // ---- setup (layer-batched) ----
    hipMemsetAsync(lq, 0, B_ROWS*sizeof(float), stream);
    hipMemsetAsync(zbias, 0, D_PAD*sizeof(float), stream);
    hipMemsetAsync(Lmb, 0, (size_t)3*N_PAD_A*D_PAD*2, stream);
    hipMemsetAsync(UpTb, 0, (size_t)3*N_PAD_A*D_PAD*2, stream);
    build_knots_kernel<<<dim3((3*F_DIM+255)/256), dim3(256), 0, stream>>>(uw_u, uh_u, ud_u, knots);
    logdiag_kernel<<<dim3(1), dim3(256), 0, stream>>>(lu_ud, logdiag);
    zero_pad_cols<<<dim3((B_ROWS*(D_PAD-D_DIM)+255)/256), dim3(256), 0, stream>>>(zbf0, zbf1);
    convert_pad<<<dim3((B_ROWS*D_PAD+255)/256), dim3(256), 0, stream>>>(
        x, xb, B_ROWS, D_DIM, B_ROWS, D_PAD);
    build_LU_bf16<<<dim3((D_DIM+255)/256, D_DIM, 3), dim3(256), 0, stream>>>(
        lu_lower, lu_upper, lu_ud, perms, Lmb, UpTb);
    gemm_mfma<1><<<dim3(5, 5, 3), dim3(256), 0, stream>>>(
        Lmb, UpTb, zbias, Apb, N_PAD_A, D_PAD, D_PAD,
        (long)N_PAD_A*D_PAD, (long)N_PAD_A*D_PAD, (long)N_PAD_A*D_PAD);
    dim3 tthr(32,8);
    transpose_convert<0><<<dim3(F_PAD/32, HID_DIM/32, 3), tthr, 0, stream>>>(
        Wi, WiT, F_DIM, HID_DIM, F_PAD, HID_DIM, (long)F_DIM*HID_DIM, (long)F_PAD*HID_DIM);
    transpose_convert<0><<<dim3(HID_DIM/32, HID_DIM/32, 12), tthr, 0, stream>>>(
        Wb, WbT, HID_DIM, HID_DIM, HID_DIM, HID_DIM, (long)HID_DIM*HID_DIM, (long)HID_DIM*HID_DIM);
    transpose_convert<1><<<dim3(HID_DIM/32, OUT_PAD/32, 3), tthr, 0, stream>>>(
        Wo, WoT, HID_DIM, OUT_DIM, HID_DIM, OUT_PAD, (long)HID_DIM*OUT_DIM, (long)OUT_PAD*HID_DIM);
    reorder_bias<<<dim3((3*OUT_PAD+255)/256), dim3(256), 0, stream>>>(bo, bo_g);

    // ---- layers ----
    const ushort_t* zcur_b = xb;
    const float* zcur_f = nullptr;
    ushort_t* zbf[2] = {zbf0, zbf1};
    float* zf[2] = {zf0, zf1};
    int zi = 0;

    for(int it=0; it<3; ++it){
        int i = 2 - it;

        // z2 = z @ Ap^T + lu_b
        gemm_mfma<0><<<dim3(N_PAD_A/128, B_ROWS/128), dim3(256), 0, stream>>>(
            zcur_b, Apb + (size_t)i*N_PAD_A*D_PAD, lu_b + (size_t)i*D_DIM,
            z2, B_ROWS, D_DIM, D_PAD, 0, 0, 0);

        ident_spline_kernel<<<dim3(B_ROWS), dim3(320), 0, stream>>>(
            z2, knots, i, identb, zf[zi], zbf[zi], lq);

        resnet_fused<<<dim3(B_ROWS/64), dim3(256), 0, stream>>>(
            identb, WiT + (size_t)i*HID_DIM*F_PAD, bi + (size_t)i*HID_DIM,
            WbT + (size_t)i*4*HID_DIM*HID_DIM, bb + (size_t)i*4*HID_DIM, tb);

        // p (full batch, grouped columns, bf16)
        gemm_mfma<1><<<dim3(OUT_PAD/128, B_ROWS/128), dim3(256), 0, stream>>>(
            tb, WoT + (size_t)i*OUT_PAD*HID_DIM, bo_g + (size_t)i*OUT_PAD,
            pbuf, B_ROWS, OUT_PAD, HID_DIM, 0, 0, 0);

        trans_spline_kernel<<<dim3(B_ROWS), dim3(320), 0, stream>>>(
            pbuf, z2, zf[zi], zbf[zi], lq);

        zcur_b = zbf[zi];
        zcur_f = zf[zi];
        zi ^= 1;
    }

    finalize_kernel<<<dim3(B_ROWS), dim3(320), 0, stream>>>(
        zcur_f, loc, lsc, lq, logdiag, out);
}

// Round 7
// 470.283 us; speedup vs baseline: 4.5495x; 1.2165x over previous
//
#include <hip/hip_runtime.h>

// ---------------------------------------------------------------------------
// DensityEstimator: 3-layer neural spline flow inverse log-prob.
// R6: Wo gemm fused into trans_spline (wo_spline): p never hits HBM
//     (52 MB x3 round-trip removed); Wo re-laid-out [f*32+j][k] so a 128-col
//     MFMA tile = 4 features; P tile in LDS fp32 [128][133] (<=2-way banks);
//     per-row ld via one atomicAdd per block. Dropped fp32 znf buffers
//     (finalize reads bf16 z). softplus log1pf -> __logf(1+x).
// ---------------------------------------------------------------------------

#define D_DIM 550
#define D_PAD 576
#define N_PAD_A 640
#define F_DIM 275
#define F_PAD 320
#define HID_DIM 128
#define OUT_DIM 6325
#define OUT_PAD 6400
#define FT_PAD 276
#define WO2_ROWS (FT_PAD*32)   // 8832 = 69*128
#define B_ROWS 4096
#define NBINS 8
#define TB_C 3.0f
#define MINB_C 0.001f
#define MIND_C 0.001f
#define DCONST_C 0.53974233f
#define LUEPS_C 0.001f
#define RSQRT_HID 0.08838834764831845f

typedef unsigned short ushort_t;
typedef __attribute__((ext_vector_type(8))) short short8;
typedef __attribute__((ext_vector_type(8))) unsigned short ushort8;
typedef __attribute__((ext_vector_type(4))) float f32x4;

__device__ __forceinline__ ushort_t f2bf(float f){
    union{float f; unsigned u;} v; v.f = f;
    unsigned r = v.u + 0x7fffu + ((v.u>>16)&1u);
    return (ushort_t)(r>>16);
}
__device__ __forceinline__ float bf2f(ushort_t h){
    union{unsigned u; float f;} v; v.u = ((unsigned)h)<<16;
    return v.f;
}
__device__ __forceinline__ float softplusf(float x){
    return fmaxf(x, 0.f) + __logf(1.f + __expf(-fabsf(x)));
}

__device__ __forceinline__ void knots_from_u(const float* u, float* c, float* w){
    float m = u[0];
#pragma unroll
    for(int k=1;k<NBINS;k++) m = fmaxf(m, u[k]);
    float e[NBINS]; float s = 0.f;
#pragma unroll
    for(int k=0;k<NBINS;k++){ e[k] = __expf(u[k]-m); s += e[k]; }
    float inv = 1.f/s;
    float cum = 0.f;
    c[0] = -TB_C;
#pragma unroll
    for(int k=0;k<NBINS;k++){
        float v = MINB_C + (1.f - MINB_C*(float)NBINS)*e[k]*inv;
        cum += v;
        c[k+1] = 2.f*TB_C*cum - TB_C;
    }
    c[NBINS] = TB_C;
#pragma unroll
    for(int k=0;k<NBINS;k++) w[k] = c[k+1]-c[k];
}

__device__ __forceinline__ void rqs_inv(float x,
                                        const float* cw, const float* w,
                                        const float* ch, const float* h,
                                        const float* d,
                                        float& out, float& ld){
    bool inside = (x >= -TB_C) && (x <= TB_C);
    float xi = fminf(fmaxf(x, -TB_C), TB_C);
    int idx = 0;
#pragma unroll
    for(int j=1;j<NBINS;j++) idx += (xi >= ch[j]) ? 1 : 0;
    float icw=cw[0], iw=w[0], ich=ch[0], ih=h[0], d0=d[0], d1=d[1];
#pragma unroll
    for(int j=1;j<NBINS;j++){
        if(idx==j){ icw=cw[j]; iw=w[j]; ich=ch[j]; ih=h[j]; d0=d[j]; d1=d[j+1]; }
    }
    float delta = ih/iw;
    float t  = xi - ich;
    float s  = d0 + d1 - 2.f*delta;
    float a  = t*s + ih*(delta - d0);
    float b  = ih*d0 - t*s;
    float c  = -delta*t;
    float disc = b*b - 4.f*a*c;
    float root = 2.f*c / (-b - sqrtf(fmaxf(disc, 0.f)));
    float o  = root*iw + icw;
    float tm = root*(1.f-root);
    float den  = delta + s*tm;
    float dnum = delta*delta*(d1*root*root + 2.f*delta*tm + d0*(1.f-root)*(1.f-root));
    float l = 2.f*__logf(den) - __logf(dnum);
    out = inside ? o : x;
    ld  = inside ? l : 0.f;
}

// --------------------------- setup kernels ---------------------------------

__global__ void build_knots_kernel(const float* __restrict__ uw_u,
                                   const float* __restrict__ uh_u,
                                   const float* __restrict__ ud_u,
                                   float* __restrict__ knots){
    int g = blockIdx.x*blockDim.x + threadIdx.x;
    if(g >= 3*F_DIM) return;
    float* kb = knots + (size_t)g*43;
    float c[9], w[8];
    knots_from_u(uw_u + (size_t)g*8, c, w);
#pragma unroll
    for(int k=0;k<9;k++) kb[k]=c[k];
#pragma unroll
    for(int k=0;k<8;k++) kb[9+k]=w[k];
    knots_from_u(uh_u + (size_t)g*8, c, w);
#pragma unroll
    for(int k=0;k<9;k++) kb[17+k]=c[k];
#pragma unroll
    for(int k=0;k<8;k++) kb[26+k]=w[k];
    float dend = MIND_C + softplusf(DCONST_C);
    kb[34]=dend; kb[42]=dend;
    const float* ud = ud_u + (size_t)g*7;
#pragma unroll
    for(int k=0;k<7;k++) kb[35+k] = MIND_C + softplusf(ud[k]);
}

__global__ void logdiag_kernel(const float* __restrict__ lu_ud, float* __restrict__ outv){
    int tid = threadIdx.x;
    float s = 0.f;
    for(int k=tid; k<3*D_DIM; k+=256) s += __logf(softplusf(lu_ud[k]) + LUEPS_C);
#pragma unroll
    for(int o=32;o>0;o>>=1) s += __shfl_down(s, o);
    __shared__ float sm[4];
    if((tid&63)==0) sm[tid>>6]=s;
    __syncthreads();
    if(tid==0) outv[0] = sm[0]+sm[1]+sm[2]+sm[3];
}

__global__ void build_LU_bf16(const float* __restrict__ lower,
                              const float* __restrict__ upper,
                              const float* __restrict__ ud,
                              const int* __restrict__ perm,
                              ushort_t* __restrict__ Lmb,
                              ushort_t* __restrict__ UpTb){
    int l = blockIdx.z;
    lower += (size_t)l*D_DIM*D_DIM; upper += (size_t)l*D_DIM*D_DIM;
    ud += (size_t)l*D_DIM; perm += (size_t)l*D_DIM;
    Lmb += (size_t)l*N_PAD_A*D_PAD; UpTb += (size_t)l*N_PAD_A*D_PAD;
    int k = blockIdx.x*blockDim.x + threadIdx.x;
    int j = blockIdx.y;
    if(k >= D_DIM) return;
    float lv = (j>k) ? lower[(size_t)j*D_DIM+k] : (j==k ? 1.f : 0.f);
    Lmb[(size_t)j*D_PAD+k] = f2bf(lv);
    float uv;
    if(j<k)       uv = upper[(size_t)j*D_DIM+k];
    else if(j==k) uv = softplusf(ud[k]) + LUEPS_C;
    else          uv = 0.f;
    UpTb[(size_t)perm[k]*D_PAD + j] = f2bf(uv);
}

__global__ void convert_pad(const float* __restrict__ in, ushort_t* __restrict__ out,
                            int M, int K, int Mpad, int Kpad){
    int idx = blockIdx.x*256 + threadIdx.x;
    if(idx >= Mpad*Kpad) return;
    int r = idx / Kpad, c = idx - r*Kpad;
    float v = (r<M && c<K) ? in[(size_t)r*K+c] : 0.f;
    out[idx] = f2bf(v);
}

template<int REMAP>
__global__ void transpose_convert(const float* __restrict__ in, ushort_t* __restrict__ out,
                                  int K, int N, int Kpad, int Npad, long s_in, long s_out){
    in += (size_t)blockIdx.z*s_in; out += (size_t)blockIdx.z*s_out;
    __shared__ float t[32][33];
    int kb = blockIdx.x*32, nb = blockIdx.y*32;
    int tx = threadIdx.x, ty = threadIdx.y;
#pragma unroll
    for(int i=0;i<32;i+=8){
        int k = kb+ty+i, n = nb+tx;
        t[ty+i][tx] = (k<K && n<N) ? in[(size_t)k*N+n] : 0.f;
    }
    __syncthreads();
#pragma unroll
    for(int i=0;i<32;i+=8){
        int n = nb+ty+i, k = kb+tx;
        if(REMAP){
            if(n < OUT_DIM && k < Kpad){
                int f = n/23, j = n - 23*f;
                out[(size_t)(f*32+j)*Kpad+k] = f2bf(t[tx][ty+i]);
            }
        } else if(n<Npad && k<Kpad){
            out[(size_t)n*Kpad+k] = f2bf(t[tx][ty+i]);
        }
    }
}

__global__ void reorder_bias(const float* __restrict__ bo, float* __restrict__ bo2){
    int idx = blockIdx.x*256 + threadIdx.x;
    if(idx >= 3*OUT_DIM) return;
    int l = idx/OUT_DIM, n = idx%OUT_DIM;
    int f = n/23, j = n - 23*f;
    bo2[(size_t)l*WO2_ROWS + f*32 + j] = bo[idx];
}

__global__ void zero_pad_cols(ushort_t* __restrict__ z0, ushort_t* __restrict__ z1){
    int idx = blockIdx.x*256 + threadIdx.x;
    if(idx >= B_ROWS*(D_PAD-D_DIM)) return;
    int r = idx/(D_PAD-D_DIM), c = D_DIM + idx%(D_PAD-D_DIM);
    z0[(size_t)r*D_PAD+c]=0; z1[(size_t)r*D_PAD+c]=0;
}

// ------------------------------ bf16 MFMA gemm -----------------------------
template<int OUTBF>
__global__ __launch_bounds__(256)
void gemm_mfma(const ushort_t* __restrict__ A, const ushort_t* __restrict__ Bt,
               const float* __restrict__ bias, void* __restrict__ Cv,
               int M, int N, int Kpad, long sA, long sB, long sC){
    A  += (size_t)blockIdx.z*sA;
    Bt += (size_t)blockIdx.z*sB;
    __shared__ ushort_t As[128][72];
    __shared__ ushort_t Bs[128][72];
    int tid = threadIdx.x;
    int row0 = blockIdx.y*128, col0 = blockIdx.x*128;
    int wave = tid>>6, lane = tid&63;
    int wm = wave&1, wn = wave>>1;
    int lm = lane&15, quad = lane>>4;
    f32x4 acc[4][4] = {};
    for(int k0=0; k0<Kpad; k0+=64){
#pragma unroll
        for(int it=0; it<4; it++){
            int c = tid + it*256;
            int r = c>>3, c8 = (c&7)*8;
            *(ushort8*)&As[r][c8] = *(const ushort8*)(A + (size_t)(row0+r)*Kpad + k0 + c8);
            *(ushort8*)&Bs[r][c8] = *(const ushort8*)(Bt + (size_t)(col0+r)*Kpad + k0 + c8);
        }
        __syncthreads();
#pragma unroll
        for(int ks=0; ks<2; ks++){
            short8 af[4], bfr[4];
#pragma unroll
            for(int i=0;i<4;i++){
                af[i]  = *(const short8*)&As[wm*64 + i*16 + lm][ks*32 + quad*8];
                bfr[i] = *(const short8*)&Bs[wn*64 + i*16 + lm][ks*32 + quad*8];
            }
#pragma unroll
            for(int i=0;i<4;i++)
#pragma unroll
                for(int j=0;j<4;j++)
                    acc[i][j] = __builtin_amdgcn_mfma_f32_16x16x32_bf16(af[i], bfr[j], acc[i][j], 0, 0, 0);
        }
        __syncthreads();
    }
#pragma unroll
    for(int i=0;i<4;i++){
        int rbase = row0 + wm*64 + i*16 + quad*4;
#pragma unroll
        for(int j=0;j<4;j++){
            int gc = col0 + wn*64 + j*16 + lm;
            if(gc >= N) continue;
            float bv = bias[gc];
#pragma unroll
            for(int r=0;r<4;r++){
                int gr = rbase + r;
                float v = acc[i][j][r] + bv;
                if(OUTBF) ((ushort_t*)Cv + (size_t)blockIdx.z*sC)[(size_t)gr*N+gc] = f2bf(v);
                else      ((float*)Cv + (size_t)blockIdx.z*sC)[(size_t)gr*N+gc] = v;
            }
        }
    }
}

// ------------------------------ fused resnet -------------------------------
__global__ __launch_bounds__(256)
void resnet_fused(const ushort_t* __restrict__ identb,
                  const ushort_t* __restrict__ WiT,
                  const float* __restrict__ bi,
                  const ushort_t* __restrict__ WbT,
                  const float* __restrict__ bb,
                  ushort_t* __restrict__ tb){
    __shared__ __align__(16) char smem[(64*136 + 128*136)*2];
    ushort_t (*As2)[136] = (ushort_t(*)[136])smem;
    ushort_t (*Ws)[136]  = (ushort_t(*)[136])(smem + 64*136*2);
    ushort_t (*As1)[72]  = (ushort_t(*)[72])smem;
    ushort_t (*Bs1)[72]  = (ushort_t(*)[72])(smem + 64*136*2);
    int tid = threadIdx.x, wave = tid>>6, lane = tid&63;
    int lm = lane&15, quad = lane>>4;
    int r0 = blockIdx.x*64;
    f32x4 cur[8] = {};
    f32x4 tsv[8];
    for(int k0=0; k0<F_PAD; k0+=64){
#pragma unroll
        for(int it=0; it<2; it++){
            int v = tid + it*256; int r = v>>3, c8 = (v&7)*8;
            *(ushort8*)&As1[r][c8] = *(const ushort8*)(identb + (size_t)(r0+r)*F_PAD + k0 + c8);
        }
#pragma unroll
        for(int it=0; it<4; it++){
            int v = tid + it*256; int n = v>>3, c8 = (v&7)*8;
            *(ushort8*)&Bs1[n][c8] = *(const ushort8*)(WiT + (size_t)n*F_PAD + k0 + c8);
        }
        __syncthreads();
#pragma unroll
        for(int ks=0; ks<2; ks++){
            short8 af = *(const short8*)&As1[wave*16 + lm][ks*32 + quad*8];
#pragma unroll
            for(int j=0;j<8;j++){
                short8 bf = *(const short8*)&Bs1[j*16 + lm][ks*32 + quad*8];
                cur[j] = __builtin_amdgcn_mfma_f32_16x16x32_bf16(af, bf, cur[j], 0, 0, 0);
            }
        }
        __syncthreads();
    }
#pragma unroll
    for(int j=0;j<8;j++){
        float bv = bi[j*16 + lm];
#pragma unroll
        for(int r=0;r<4;r++) cur[j][r] += bv;
        tsv[j] = cur[j];
    }
    for(int st=0; st<4; st++){
#pragma unroll
        for(int j=0;j<8;j++)
#pragma unroll
            for(int r=0;r<4;r++)
                As2[wave*16 + quad*4 + r][j*16 + lm] = f2bf(fmaxf(cur[j][r], 0.f));
#pragma unroll
        for(int it=0; it<8; it++){
            int v = tid + it*256; int n = v>>4, c8 = (v&15)*8;
            *(ushort8*)&Ws[n][c8] = *(const ushort8*)(WbT + (size_t)st*128*128 + (size_t)n*128 + c8);
        }
        __syncthreads();
        f32x4 acc[8] = {};
#pragma unroll
        for(int ks=0; ks<4; ks++){
            short8 af = *(const short8*)&As2[wave*16 + lm][ks*32 + quad*8];
#pragma unroll
            for(int j=0;j<8;j++){
                short8 bf = *(const short8*)&Ws[j*16 + lm][ks*32 + quad*8];
                acc[j] = __builtin_amdgcn_mfma_f32_16x16x32_bf16(af, bf, acc[j], 0, 0, 0);
            }
        }
        __syncthreads();
#pragma unroll
        for(int j=0;j<8;j++){
            float bv = bb[st*128 + j*16 + lm];
#pragma unroll
            for(int r=0;r<4;r++) acc[j][r] += bv;
        }
        if(st==1 || st==3){
#pragma unroll
            for(int j=0;j<8;j++){
#pragma unroll
                for(int r=0;r<4;r++) acc[j][r] += tsv[j][r];
                tsv[j] = acc[j];
            }
        }
#pragma unroll
        for(int j=0;j<8;j++) cur[j] = acc[j];
    }
#pragma unroll
    for(int j=0;j<8;j++)
#pragma unroll
        for(int r=0;r<4;r++)
            tb[(size_t)(r0 + wave*16 + quad*4 + r)*HID_DIM + j*16 + lm] = f2bf(cur[j][r]);
}

// ----------------------- fused Wo gemm + trans spline ----------------------
__global__ __launch_bounds__(256)
void wo_spline(const ushort_t* __restrict__ tb,
               const ushort_t* __restrict__ Wo2,
               const float* __restrict__ bo2,
               const float* __restrict__ z2,
               ushort_t* __restrict__ znb,
               float* __restrict__ lq){
    __shared__ __align__(16) char smem[128*133*4];
    __shared__ float ldred[128];
    ushort_t (*As)[72] = (ushort_t(*)[72])smem;
    ushort_t (*Bs)[72] = (ushort_t(*)[72])(smem + 128*72*2);
    float (*P)[133] = (float(*)[133])smem;
    int tid = threadIdx.x;
    int row0 = blockIdx.y*128, col0 = blockIdx.x*128;
    int wave = tid>>6, lane = tid&63;
    int wm = wave&1, wn = wave>>1;
    int lm = lane&15, quad = lane>>4;
    f32x4 acc[4][4] = {};
    for(int k0=0; k0<HID_DIM; k0+=64){
#pragma unroll
        for(int it=0; it<4; it++){
            int c = tid + it*256;
            int r = c>>3, c8 = (c&7)*8;
            *(ushort8*)&As[r][c8] = *(const ushort8*)(tb + (size_t)(row0+r)*HID_DIM + k0 + c8);
            *(ushort8*)&Bs[r][c8] = *(const ushort8*)(Wo2 + (size_t)(col0+r)*HID_DIM + k0 + c8);
        }
        __syncthreads();
#pragma unroll
        for(int ks=0; ks<2; ks++){
            short8 af[4], bfr[4];
#pragma unroll
            for(int i=0;i<4;i++){
                af[i]  = *(const short8*)&As[wm*64 + i*16 + lm][ks*32 + quad*8];
                bfr[i] = *(const short8*)&Bs[wn*64 + i*16 + lm][ks*32 + quad*8];
            }
#pragma unroll
            for(int i=0;i<4;i++)
#pragma unroll
                for(int j=0;j<4;j++)
                    acc[i][j] = __builtin_amdgcn_mfma_f32_16x16x32_bf16(af[i], bfr[j], acc[i][j], 0, 0, 0);
        }
        __syncthreads();
    }
#pragma unroll
    for(int j=0;j<4;j++){
        int cl = wn*64 + j*16 + lm;
        float bv = bo2[col0 + cl];
#pragma unroll
        for(int i=0;i<4;i++){
            int rl = wm*64 + i*16 + quad*4;
#pragma unroll
            for(int r=0;r<4;r++) P[rl+r][cl] = acc[i][j][r] + bv;
        }
    }
    __syncthreads();
    int row = tid & 127;
    int fbase = col0 >> 5;
    float ldsum = 0.f;
#pragma unroll
    for(int e=0;e<2;e++){
        int feat = (tid>>7) + e*2;
        int fg = fbase + feat;
        if(fg < F_DIM){
            const float* q = &P[row][feat*32];
            float uw[8], uh[8];
#pragma unroll
            for(int c=0;c<8;c++){ uw[c] = q[c]*RSQRT_HID; uh[c] = q[8+c]*RSQRT_HID; }
            float cw[9], w[8], ch[9], h[8], d[9];
            knots_from_u(uw, cw, w);
            knots_from_u(uh, ch, h);
            float dend = MIND_C + softplusf(DCONST_C);
            d[0]=dend; d[8]=dend;
#pragma unroll
            for(int c=0;c<7;c++) d[c+1] = MIND_C + softplusf(q[16+c]);
            float xv = z2[(size_t)(row0+row)*D_DIM + 2*fg + 1];
            float o, l;
            rqs_inv(xv, cw, w, ch, h, d, o, l);
            znb[(size_t)(row0+row)*D_PAD + 2*fg + 1] = f2bf(o);
            ldsum += l;
        }
    }
    if(tid >= 128) ldred[tid-128] = ldsum;
    __syncthreads();
    if(tid < 128) atomicAdd(&lq[row0+tid], ldsum + ldred[tid]);
}

// --------------------------- spline kernels --------------------------------

__global__ __launch_bounds__(320)
void ident_spline_kernel(const float* __restrict__ z2, const float* __restrict__ knots,
                         int layer, ushort_t* __restrict__ identb,
                         ushort_t* __restrict__ znb, float* __restrict__ lq){
    int row = blockIdx.x; int tid = threadIdx.x;
    float ldv = 0.f;
    if(tid < F_DIM){
        const float* kb = knots + ((size_t)(layer*F_DIM + tid))*43;
        float x = z2[(size_t)row*D_DIM + 2*tid];
        float o, l;
        rqs_inv(x, kb, kb+9, kb+17, kb+26, kb+34, o, l);
        identb[(size_t)row*F_PAD + tid] = f2bf(o);
        znb[(size_t)row*D_PAD + 2*tid] = f2bf(o);
        ldv = l;
    } else {
        identb[(size_t)row*F_PAD + tid] = 0;
    }
    __shared__ float sm[5];
    float v = ldv;
#pragma unroll
    for(int o=32;o>0;o>>=1) v += __shfl_down(v, o);
    if((tid&63)==0) sm[tid>>6]=v;
    __syncthreads();
    if(tid==0) lq[row] += sm[0]+sm[1]+sm[2]+sm[3]+sm[4];
}

__global__ __launch_bounds__(320)
void finalize_kernel(const ushort_t* __restrict__ zb, const float* __restrict__ loc,
                     const float* __restrict__ lsc, const float* __restrict__ lq,
                     const float* __restrict__ logdiag, float* __restrict__ out){
    int row = blockIdx.x; int tid = threadIdx.x;
    float s = 0.f;
    for(int k=tid; k<D_DIM; k+=320){
        float l = lsc[k];
        float diff = (bf2f(zb[(size_t)row*D_PAD+k])-loc[k])*__expf(-l);
        s += l + 0.5f*diff*diff;
    }
    __shared__ float sm[5];
#pragma unroll
    for(int o=32;o>0;o>>=1) s += __shfl_down(s, o);
    if((tid&63)==0) sm[tid>>6]=s;
    __syncthreads();
    if(tid==0){
        float tot = sm[0]+sm[1]+sm[2]+sm[3]+sm[4];
        out[row] = lq[row] + logdiag[0] - 275.f*1.8378770664f - tot;
    }
}

// ---------------------------------------------------------------------------

extern "C" void kernel_launch(void* const* d_in, const int* in_sizes, int n_in,
                              void* d_out, int out_size, void* d_ws, size_t ws_size,
                              hipStream_t stream){
    const float* x        = (const float*)d_in[0];
    const float* loc      = (const float*)d_in[1];
    const float* lsc      = (const float*)d_in[2];
    const float* Wi       = (const float*)d_in[3];
    const float* bi       = (const float*)d_in[4];
    const float* Wb       = (const float*)d_in[5];
    const float* bb       = (const float*)d_in[6];
    const float* Wo       = (const float*)d_in[7];
    const float* bo       = (const float*)d_in[8];
    const float* uw_u     = (const float*)d_in[9];
    const float* uh_u     = (const float*)d_in[10];
    const float* ud_u     = (const float*)d_in[11];
    const float* lu_lower = (const float*)d_in[12];
    const float* lu_upper = (const float*)d_in[13];
    const float* lu_ud    = (const float*)d_in[14];
    const float* lu_b     = (const float*)d_in[15];
    const int*   perms    = (const int*)d_in[16];
    float* out = (float*)d_out;

    char* base = (char*)d_ws;
    size_t off = 0;
    auto alloc = [&](size_t bytes)->char*{
        char* p = base + off;
        off += (bytes + 255) & ~(size_t)255;
        return p;
    };
    float* lq      = (float*)alloc(B_ROWS*4);
    float* zbias   = (float*)alloc(D_PAD*4);
    float* logdiag = (float*)alloc(64*4);
    float* knots   = (float*)alloc((size_t)3*F_DIM*43*4);
    float* z2      = (float*)alloc((size_t)B_ROWS*D_DIM*4);
    float* bo2     = (float*)alloc((size_t)3*WO2_ROWS*4);
    ushort_t* xb   = (ushort_t*)alloc((size_t)B_ROWS*D_PAD*2);
    ushort_t* zbf0 = (ushort_t*)alloc((size_t)B_ROWS*D_PAD*2);
    ushort_t* zbf1 = (ushort_t*)alloc((size_t)B_ROWS*D_PAD*2);
    ushort_t* Lmb  = (ushort_t*)alloc((size_t)3*N_PAD_A*D_PAD*2);
    ushort_t* UpTb = (ushort_t*)alloc((size_t)3*N_PAD_A*D_PAD*2);
    ushort_t* Apb  = (ushort_t*)alloc((size_t)3*N_PAD_A*D_PAD*2);
    ushort_t* identb=(ushort_t*)alloc((size_t)B_ROWS*F_PAD*2);
    ushort_t* tb   = (ushort_t*)alloc((size_t)B_ROWS*HID_DIM*2);
    ushort_t* WiT  = (ushort_t*)alloc((size_t)3*HID_DIM*F_PAD*2);
    ushort_t* WbT  = (ushort_t*)alloc((size_t)3*4*HID_DIM*HID_DIM*2);
    ushort_t* Wo2  = (ushort_t*)alloc((size_t)3*WO2_ROWS*HID_DIM*2);

    hipMemsetAsync(lq, 0, B_ROWS*sizeof(float), stream);
    hipMemsetAsync(zbias, 0, D_PAD*sizeof(float), stream);
    hipMemsetAsync(Lmb, 0, (size_t)3*N_PAD_A*D_PAD*2, stream);
    hipMemsetAsync(UpTb, 0, (size_t)3*N_PAD_A*D_PAD*2, stream);
    hipMemsetAsync(Wo2, 0, (size_t)3*WO2_ROWS*HID_DIM*2, stream);
    hipMemsetAsync(bo2, 0, (size_t)3*WO2_ROWS*4, stream);
    build_knots_kernel<<<dim3((3*F_DIM+255)/256), dim3(256), 0, stream>>>(uw_u, uh_u, ud_u, knots);
    logdiag_kernel<<<dim3(1), dim3(256), 0, stream>>>(lu_ud, logdiag);
    zero_pad_cols<<<dim3((B_ROWS*(D_PAD-D_DIM)+255)/256), dim3(256), 0, stream>>>(zbf0, zbf1);
    convert_pad<<<dim3((B_ROWS*D_PAD+255)/256), dim3(256), 0, stream>>>(
        x, xb, B_ROWS, D_DIM, B_ROWS, D_PAD);
    build_LU_bf16<<<dim3((D_DIM+255)/256, D_DIM, 3), dim3(256), 0, stream>>>(
        lu_lower, lu_upper, lu_ud, perms, Lmb, UpTb);
    gemm_mfma<1><<<dim3(5, 5, 3), dim3(256), 0, stream>>>(
        Lmb, UpTb, zbias, Apb, N_PAD_A, D_PAD, D_PAD,
        (long)N_PAD_A*D_PAD, (long)N_PAD_A*D_PAD, (long)N_PAD_A*D_PAD);
    dim3 tthr(32,8);
    transpose_convert<0><<<dim3(F_PAD/32, HID_DIM/32, 3), tthr, 0, stream>>>(
        Wi, WiT, F_DIM, HID_DIM, F_PAD, HID_DIM, (long)F_DIM*HID_DIM, (long)F_PAD*HID_DIM);
    transpose_convert<0><<<dim3(HID_DIM/32, HID_DIM/32, 12), tthr, 0, stream>>>(
        Wb, WbT, HID_DIM, HID_DIM, HID_DIM, HID_DIM, (long)HID_DIM*HID_DIM, (long)HID_DIM*HID_DIM);
    transpose_convert<1><<<dim3(HID_DIM/32, OUT_PAD/32, 3), tthr, 0, stream>>>(
        Wo, Wo2, HID_DIM, OUT_DIM, HID_DIM, OUT_PAD, (long)HID_DIM*OUT_DIM, (long)WO2_ROWS*HID_DIM);
    reorder_bias<<<dim3((3*OUT_DIM+255)/256), dim3(256), 0, stream>>>(bo, bo2);

    const ushort_t* zcur_b = xb;
    ushort_t* zbf[2] = {zbf0, zbf1};
    int zi = 0;

    for(int it=0; it<3; ++it){
        int i = 2 - it;

        gemm_mfma<0><<<dim3(N_PAD_A/128, B_ROWS/128), dim3(256), 0, stream>>>(
            zcur_b, Apb + (size_t)i*N_PAD_A*D_PAD, lu_b + (size_t)i*D_DIM,
            z2, B_ROWS, D_DIM, D_PAD, 0, 0, 0);

        ident_spline_kernel<<<dim3(B_ROWS), dim3(320), 0, stream>>>(
            z2, knots, i, identb, zbf[zi], lq);

        resnet_fused<<<dim3(B_ROWS/64), dim3(256), 0, stream>>>(
            identb, WiT + (size_t)i*HID_DIM*F_PAD, bi + (size_t)i*HID_DIM,
            WbT + (size_t)i*4*HID_DIM*HID_DIM, bb + (size_t)i*4*HID_DIM, tb);

        wo_spline<<<dim3(WO2_ROWS/128, B_ROWS/128), dim3(256), 0, stream>>>(
            tb, Wo2 + (size_t)i*WO2_ROWS*HID_DIM, bo2 + (size_t)i*WO2_ROWS,
            z2, zbf[zi], lq);

        zcur_b = zbf[zi];
        zi ^= 1;
    }

    finalize_kernel<<<dim3(B_ROWS), dim3(320), 0, stream>>>(
        zcur_b, loc, lsc, lq, logdiag, out);
}